// Round 8
// baseline (3104.362 us; speedup 1.0000x reference)
//
#include <hip/hip_runtime.h>

#define NN   50000
#define NE   800000
#define INCH 8
#define CH   128
#define EA   6
#define NB   2000
#define NCLS 32
#define FUS  384

// ---------- bf16 helpers (RTNE pack, exact unpack) ----------
static __device__ __forceinline__ unsigned short f2bf(float f) {
  unsigned u = __float_as_uint(f);
  u += 0x7fffu + ((u >> 16) & 1u);
  return (unsigned short)(u >> 16);
}
static __device__ __forceinline__ unsigned pack2(float x, float y) {
  return (unsigned)f2bf(x) | ((unsigned)f2bf(y) << 16);
}
static __device__ __forceinline__ float2 unpack2(unsigned u) {
  float2 r;
  r.x = __uint_as_float(u << 16);
  r.y = __uint_as_float(u & 0xffff0000u);
  return r;
}

// ---------- degree of dst nodes ----------
__global__ __launch_bounds__(256) void k_deg(const int* __restrict__ edge,
                                             int* __restrict__ deg) {
  int e = blockIdx.x * 256 + threadIdx.x;
  if (e < NE) atomicAdd(&deg[edge[NE + e]], 1);
}

// ---------- exclusive scan of deg -> row_ptr (single block, shfl scan) ----------
__global__ __launch_bounds__(1024) void k_scan(const int* __restrict__ deg,
                                               int* __restrict__ row_ptr) {
  __shared__ int wsum[16];
  __shared__ int s_carry;
  const int t = threadIdx.x, lane = t & 63, w = t >> 6;
  if (t == 0) s_carry = 0;
  __syncthreads();
  for (int base = 0; base < NN; base += 1024) {
    int i = base + t;
    int x = (i < NN) ? deg[i] : 0;
#pragma unroll
    for (int off = 1; off < 64; off <<= 1) {
      int y = __shfl_up(x, off, 64);
      if (lane >= off) x += y;
    }
    if (lane == 63) wsum[w] = x;
    __syncthreads();
    if (w == 0 && lane < 16) {
      int s = wsum[lane];
#pragma unroll
      for (int off = 1; off < 16; off <<= 1) {
        int y = __shfl_up(s, off, 64);
        if (lane >= off) s += y;
      }
      wsum[lane] = s;
    }
    __syncthreads();
    int incl = x + ((w == 0) ? 0 : wsum[w - 1]) + s_carry;
    if (i < NN) row_ptr[i + 1] = incl;
    __syncthreads();
    if (t == 1023) s_carry = incl;
    __syncthreads();
  }
  if (t == 0) row_ptr[0] = 0;
}

// ---------- fill CSR: edge ids grouped by dst ----------
__global__ __launch_bounds__(256) void k_fill(
    const int* __restrict__ edge, const int* __restrict__ row_ptr,
    int* __restrict__ cursor, int* __restrict__ eid_arr) {
  int e = blockIdx.x * 256 + threadIdx.x;
  if (e >= NE) return;
  int d = edge[NE + e];
  int idx = row_ptr[d] + atomicAdd(&cursor[d], 1);
  eid_arr[idx] = e;
}

// ---------- segment starts from sorted bbox_idx ----------
__global__ __launch_bounds__(256) void k_segstart(const int* __restrict__ bbox,
                                                  int* __restrict__ seg) {
  int i = blockIdx.x * 256 + threadIdx.x;
  if (i >= NN) return;
  int bc = bbox[i];
  int bp = (i == 0) ? -1 : bbox[i - 1];
  for (int j = bp + 1; j <= bc; ++j) seg[j] = i;
  if (i == NN - 1)
    for (int j = bc + 1; j <= NB; ++j) seg[j] = NN;
}

// ---------- dual-stream node transform -> bf16 P/Q for both streams ----------
// Pn = X1@(Wn1-Wn2)+bn, Qn = X1@Wn2 ; Ps = X2@(Ws1-Ws2)+bs, Qs = X2@Ws2
// Block = 4 waves x 8 nodes. Lane-distributed x (8 nodes x 8 k per load),
// consumed via static __shfl (v_readlane -> SGPR FMA operand).
__global__ __launch_bounds__(256) void k_node_pq2(
    const float* __restrict__ X1, const float* __restrict__ X2, int ldx, int K,
    const float* __restrict__ Wn, const float* __restrict__ bn,
    const float* __restrict__ Ws, const float* __restrict__ bs,
    unsigned* __restrict__ Pn, unsigned* __restrict__ Qn,
    unsigned* __restrict__ Ps, unsigned* __restrict__ Qs) {
  const int t = threadIdx.x, lane = t & 63, wv = t >> 6;
  const int nbase = blockIdx.x * 32 + wv * 8;
  const int c = lane * 2;
  const float2 bvn = *(const float2*)(bn + c);
  const float2 bvs = *(const float2*)(bs + c);
  float2 pan[8], qan[8], pas[8], qas[8];
#pragma unroll
  for (int u = 0; u < 8; ++u) {
    pan[u] = bvn; pas[u] = bvs;
    qan[u] = make_float2(0.f, 0.f); qas[u] = make_float2(0.f, 0.f);
  }
  const int xrow = min(nbase + (lane >> 3), NN - 1);
  const int xk = lane & 7;
  for (int k0 = 0; k0 < K; k0 += 8) {
    const float xv1 = X1[(size_t)xrow * ldx + k0 + xk];
    const float xv2 = X2[(size_t)xrow * ldx + k0 + xk];
#pragma unroll
    for (int j = 0; j < 8; ++j) {
      const float2 wn1 = *(const float2*)(Wn + (size_t)(k0 + j) * CH + c);
      const float2 wn2 = *(const float2*)(Wn + (size_t)(K + k0 + j) * CH + c);
      const float2 ws1 = *(const float2*)(Ws + (size_t)(k0 + j) * CH + c);
      const float2 ws2 = *(const float2*)(Ws + (size_t)(K + k0 + j) * CH + c);
      const float2 wdn = {wn1.x - wn2.x, wn1.y - wn2.y};
      const float2 wds = {ws1.x - ws2.x, ws1.y - ws2.y};
#pragma unroll
      for (int u = 0; u < 8; ++u) {
        const float x1 = __shfl(xv1, u * 8 + j, 64);
        const float x2 = __shfl(xv2, u * 8 + j, 64);
        pan[u].x += x1 * wdn.x; pan[u].y += x1 * wdn.y;
        qan[u].x += x1 * wn2.x; qan[u].y += x1 * wn2.y;
        pas[u].x += x2 * wds.x; pas[u].y += x2 * wds.y;
        qas[u].x += x2 * ws2.x; qas[u].y += x2 * ws2.y;
      }
    }
  }
#pragma unroll
  for (int u = 0; u < 8; ++u) {
    const int node = nbase + u;
    if (node < NN) {
      const size_t o = (size_t)node * 64 + lane;
      Pn[o] = pack2(pan[u].x, pan[u].y);
      Qn[o] = pack2(qan[u].x, qan[u].y);
      Ps[o] = pack2(pas[u].x, pas[u].y);
      Qs[o] = pack2(qas[u].x, qas[u].y);
    }
  }
}

// ---------- dual-stream CSR conv: one node/WAVE, shared edge meta + shfl ----
// node stream: feats[cur] = max_e relu(Pn[s]+Qn[d]+e@Cn)  (+feats[prev])
// super stream: sfeats[cur] = mean_e relu(Ps[s]+Qs[d]+e@Cs) (+sfeats[prev])
__global__ __launch_bounds__(256) void k_conv2(
    const int* __restrict__ row_ptr, const int* __restrict__ eid_arr,
    const int* __restrict__ edge, const float* __restrict__ eattr,
    const unsigned* __restrict__ Pn, const unsigned* __restrict__ Qn,
    const unsigned* __restrict__ Ps, const unsigned* __restrict__ Qs,
    const float* __restrict__ Cn, const float* __restrict__ Cs,
    float* __restrict__ feats, float* __restrict__ sfeats,
    int cur, int prev) {
  const int t = threadIdx.x;
  const int lane = t & 63;
  const int node = blockIdx.x * 4 + (t >> 6);
  const int c = lane * 2;
  float2 cwn[EA], cws[EA];
#pragma unroll
  for (int j = 0; j < EA; ++j) {
    cwn[j] = *(const float2*)(Cn + j * CH + c);
    cws[j] = *(const float2*)(Cs + j * CH + c);
  }
  int i0 = __builtin_amdgcn_readfirstlane(row_ptr[node]);
  int i1 = __builtin_amdgcn_readfirstlane(row_ptr[node + 1]);
  const float2 qn = unpack2(Qn[(size_t)node * 64 + lane]);
  const float2 qs = unpack2(Qs[(size_t)node * 64 + lane]);
  float an0 = 0.f, an1 = 0.f, as0 = 0.f, as1 = 0.f;
  for (int base = i0; base < i1; base += 64) {
    const int cnt = min(64, i1 - base);
    int s_l = 0;
    float ea0 = 0.f, ea1 = 0.f, ea2 = 0.f, ea3 = 0.f, ea4 = 0.f, ea5 = 0.f;
    if (lane < cnt) {
      int e = eid_arr[base + lane];      // coalesced
      s_l = edge[e];                     // gather
      const float* ep = eattr + (size_t)e * EA;
      ea0 = ep[0]; ea1 = ep[1]; ea2 = ep[2];
      ea3 = ep[3]; ea4 = ep[4]; ea5 = ep[5];
    }
#define EDGE_BODY(J)                                                       \
    {                                                                      \
      int s = __shfl(s_l, (J), 64);                                        \
      float e0 = __shfl(ea0, (J), 64), e1 = __shfl(ea1, (J), 64);          \
      float e2 = __shfl(ea2, (J), 64), e3 = __shfl(ea3, (J), 64);          \
      float e4 = __shfl(ea4, (J), 64), e5 = __shfl(ea5, (J), 64);          \
      const float2 pn = unpack2(Pn[(size_t)s * 64 + lane]);                \
      const float2 ps = unpack2(Ps[(size_t)s * 64 + lane]);                \
      float vn0 = pn.x + qn.x, vn1 = pn.y + qn.y;                          \
      float vs0 = ps.x + qs.x, vs1 = ps.y + qs.y;                          \
      vn0 += e0 * cwn[0].x; vn1 += e0 * cwn[0].y;                          \
      vs0 += e0 * cws[0].x; vs1 += e0 * cws[0].y;                          \
      vn0 += e1 * cwn[1].x; vn1 += e1 * cwn[1].y;                          \
      vs0 += e1 * cws[1].x; vs1 += e1 * cws[1].y;                          \
      vn0 += e2 * cwn[2].x; vn1 += e2 * cwn[2].y;                          \
      vs0 += e2 * cws[2].x; vs1 += e2 * cws[2].y;                          \
      vn0 += e3 * cwn[3].x; vn1 += e3 * cwn[3].y;                          \
      vs0 += e3 * cws[3].x; vs1 += e3 * cws[3].y;                          \
      vn0 += e4 * cwn[4].x; vn1 += e4 * cwn[4].y;                          \
      vs0 += e4 * cws[4].x; vs1 += e4 * cws[4].y;                          \
      vn0 += e5 * cwn[5].x; vn1 += e5 * cwn[5].y;                          \
      vs0 += e5 * cws[5].x; vs1 += e5 * cws[5].y;                          \
      an0 = fmaxf(an0, vn0); an1 = fmaxf(an1, vn1);                        \
      as0 += fmaxf(vs0, 0.f); as1 += fmaxf(vs1, 0.f);                      \
    }
    int j = 0;
    for (; j + 4 <= cnt; j += 4) {
      EDGE_BODY(j) EDGE_BODY(j + 1) EDGE_BODY(j + 2) EDGE_BODY(j + 3)
    }
    for (; j < cnt; ++j) EDGE_BODY(j)
#undef EDGE_BODY
  }
  const float inv = 1.f / fmaxf((float)(i1 - i0), 1.f);
  as0 *= inv; as1 *= inv;
  const size_t o = (size_t)node * FUS + (size_t)cur * CH + c;
  if (prev >= 0) {
    const size_t op = (size_t)node * FUS + (size_t)prev * CH + c;
    const float2 prn = *(const float2*)(feats + op);
    const float2 prs = *(const float2*)(sfeats + op);
    an0 += prn.x; an1 += prn.y;
    as0 += prs.x; as1 += prs.y;
  }
  float2 on = {an0, an1}, os = {as0, as1};
  *(float2*)(feats + o) = on;
  *(float2*)(sfeats + o) = os;
}

// ---------- fusion GEMM (LDS-staged W) + segment max via atomicMax ----------
// Block: 32 nodes (4 waves x 8) x 512 cols. W tile 16x512 staged in LDS (32 KB)
// once per k-slice -> W L2 traffic 9.4 GB -> 2.3 GB. Thread owns cols
// {colA..colA+3, colA+256..+259} -> contiguous-16B ds_read_b128, conflict-free.
// Epilogue: bias+relu, per-thread run-merge over sorted bbox ids, atomicMax
// (uint bit-pattern max == float max for relu>=0 outputs, pooled pre-zeroed).
__global__ __launch_bounds__(256) void k_pool_gemm(
    const float* __restrict__ feats, const int* __restrict__ bbox,
    const float* __restrict__ Wf, const float* __restrict__ bf,
    float* __restrict__ pooled) {
  __shared__ float wlds[16 * 512];  // 32 KB
  const int t = threadIdx.x, lane = t & 63, wv = t >> 6;
  const int nbase = blockIdx.x * 32 + wv * 8;
  const int colA = blockIdx.y * 512 + lane * 4;   // + cols colA+256..259
  float acc[8][8];
#pragma unroll
  for (int u = 0; u < 8; ++u)
#pragma unroll
    for (int i = 0; i < 8; ++i) acc[u][i] = 0.f;
  const int xrow = min(nbase + (lane >> 3), NN - 1);
  const int xk = lane & 7;
  for (int k0 = 0; k0 < FUS; k0 += 16) {
    __syncthreads();
#pragma unroll
    for (int r = 0; r < 8; ++r) {     // stage 16x512 floats, 256 thr x 8 float4
      const int f4 = r * 256 + t;
      const int kk = f4 >> 7, c4 = f4 & 127;
      *(float4*)&wlds[kk * 512 + c4 * 4] =
          *(const float4*)(Wf + (size_t)(k0 + kk) * 1024 + blockIdx.y * 512 + c4 * 4);
    }
    __syncthreads();
#pragma unroll
    for (int h = 0; h < 2; ++h) {
      const float xv = feats[(size_t)xrow * FUS + k0 + h * 8 + xk];
#pragma unroll
      for (int j = 0; j < 8; ++j) {
        const float4 w0 = *(const float4*)&wlds[(h * 8 + j) * 512 + lane * 4];
        const float4 w1 = *(const float4*)&wlds[(h * 8 + j) * 512 + 256 + lane * 4];
#pragma unroll
        for (int u = 0; u < 8; ++u) {
          const float xs = __shfl(xv, u * 8 + j, 64);
          acc[u][0] += xs * w0.x; acc[u][1] += xs * w0.y;
          acc[u][2] += xs * w0.z; acc[u][3] += xs * w0.w;
          acc[u][4] += xs * w1.x; acc[u][5] += xs * w1.y;
          acc[u][6] += xs * w1.z; acc[u][7] += xs * w1.w;
        }
      }
    }
  }
  float b8[8];
  *(float4*)&b8[0] = *(const float4*)(bf + colA);
  *(float4*)&b8[4] = *(const float4*)(bf + colA + 256);
  int curb = -1;
  float m[8];
#pragma unroll
  for (int i = 0; i < 8; ++i) m[i] = 0.f;
#pragma unroll
  for (int u = 0; u < 8; ++u) {
    const int node = nbase + u;
    if (node < NN) {                      // wave-uniform guard
      const int bid = bbox[node];
      float v[8];
#pragma unroll
      for (int i = 0; i < 8; ++i) v[i] = fmaxf(acc[u][i] + b8[i], 0.f);
      if (bid != curb) {
        if (curb >= 0) {
#pragma unroll
          for (int i = 0; i < 4; ++i)
            atomicMax((unsigned*)(pooled + (size_t)curb * 1408 + colA + i),
                      __float_as_uint(m[i]));
#pragma unroll
          for (int i = 4; i < 8; ++i)
            atomicMax((unsigned*)(pooled + (size_t)curb * 1408 + colA + 252 + i),
                      __float_as_uint(m[i]));
        }
        curb = bid;
#pragma unroll
        for (int i = 0; i < 8; ++i) m[i] = v[i];
      } else {
#pragma unroll
        for (int i = 0; i < 8; ++i) m[i] = fmaxf(m[i], v[i]);
      }
    }
  }
  if (curb >= 0) {
#pragma unroll
    for (int i = 0; i < 4; ++i)
      atomicMax((unsigned*)(pooled + (size_t)curb * 1408 + colA + i),
                __float_as_uint(m[i]));
#pragma unroll
    for (int i = 4; i < 8; ++i)
      atomicMax((unsigned*)(pooled + (size_t)curb * 1408 + colA + 252 + i),
                __float_as_uint(m[i]));
  }
}

// ---------- raw-feats bbox max + sfeats bbox mean ----------
__global__ __launch_bounds__(256) void k_poolraw(
    const float* __restrict__ feats, const float* __restrict__ sfeats,
    const int* __restrict__ seg, float* __restrict__ pooled,
    float* __restrict__ sb) {
  const int b = blockIdx.x, t = threadIdx.x;
  if (t >= 192) return;
  const int c2 = t * 2;
  const int n0 = __builtin_amdgcn_readfirstlane(seg[b]);
  const int n1 = __builtin_amdgcn_readfirstlane(seg[b + 1]);
  float2 fmx = {0.f, 0.f}, ss = {0.f, 0.f};
  for (int n = n0; n < n1; ++n) {
    const float2 f2 = *(const float2*)(feats + (size_t)n * FUS + c2);
    fmx.x = fmaxf(fmx.x, f2.x); fmx.y = fmaxf(fmx.y, f2.y);
    const float2 s2 = *(const float2*)(sfeats + (size_t)n * FUS + c2);
    ss.x += s2.x; ss.y += s2.y;
  }
  *(float2*)(pooled + (size_t)b * 1408 + 1024 + c2) = fmx;
  const float inv = 1.f / fmaxf((float)(n1 - n0), 1.f);
  float2 o = {ss.x * inv, ss.y * inv};
  *(float2*)(sb + (size_t)b * FUS + c2) = o;
}

// ---------- fusion_super = relu(sb @ Wfs + bfs) ----------
__global__ __launch_bounds__(256) void k_fusion_super(
    const float* __restrict__ sb, const float* __restrict__ Wfs,
    const float* __restrict__ bfs, float* __restrict__ fs) {
  const int r0 = blockIdx.x * 8, t = threadIdx.x;
  float acc[8][4];
#pragma unroll
  for (int u = 0; u < 8; ++u)
    acc[u][0] = acc[u][1] = acc[u][2] = acc[u][3] = 0.f;
  for (int k = 0; k < FUS; ++k) {
    const float4 w = *(const float4*)(Wfs + (size_t)k * 1024 + t * 4);
#pragma unroll
    for (int u = 0; u < 8; ++u) {
      float x = sb[(size_t)(r0 + u) * FUS + k];
      acc[u][0] += x * w.x; acc[u][1] += x * w.y;
      acc[u][2] += x * w.z; acc[u][3] += x * w.w;
    }
  }
  const float4 b4 = *(const float4*)(bfs + t * 4);
#pragma unroll
  for (int u = 0; u < 8; ++u) {
    float4 o = {fmaxf(acc[u][0] + b4.x, 0.f), fmaxf(acc[u][1] + b4.y, 0.f),
                fmaxf(acc[u][2] + b4.z, 0.f), fmaxf(acc[u][3] + b4.w, 0.f)};
    *(float4*)(fs + (size_t)(r0 + u) * 1024 + t * 4) = o;
  }
}

// ---------- h1 = relu(concat(pooled, fs, sb) @ W1 + b1), column-split ----------
__global__ __launch_bounds__(256) void k_mlp1(
    const float* __restrict__ pooled, const float* __restrict__ fs,
    const float* __restrict__ sb, const float* __restrict__ W1,
    const float* __restrict__ b1, float* __restrict__ h1) {
  const int r0 = blockIdx.x * 8;
  const int col = blockIdx.y * 256 + threadIdx.x;
  float acc[8];
#pragma unroll
  for (int u = 0; u < 8; ++u) acc[u] = 0.f;
  for (int k = 0; k < 1408; ++k) {
    float w = W1[(size_t)k * 512 + col];
#pragma unroll
    for (int u = 0; u < 8; ++u) acc[u] += pooled[(size_t)(r0 + u) * 1408 + k] * w;
  }
  for (int k = 0; k < 1024; ++k) {
    float w = W1[(size_t)(1408 + k) * 512 + col];
#pragma unroll
    for (int u = 0; u < 8; ++u) acc[u] += fs[(size_t)(r0 + u) * 1024 + k] * w;
  }
  for (int k = 0; k < FUS; ++k) {
    float w = W1[(size_t)(2432 + k) * 512 + col];
#pragma unroll
    for (int u = 0; u < 8; ++u) acc[u] += sb[(size_t)(r0 + u) * FUS + k] * w;
  }
  float bv = b1[col];
#pragma unroll
  for (int u = 0; u < 8; ++u)
    h1[(size_t)(r0 + u) * 512 + col] = fmaxf(acc[u] + bv, 0.f);
}

// ---------- h2 = relu(h1 @ W2 + b2) ----------
__global__ __launch_bounds__(256) void k_mlp2(
    const float* __restrict__ h1, const float* __restrict__ W2,
    const float* __restrict__ b2, float* __restrict__ h2) {
  const int r0 = blockIdx.x * 8, t = threadIdx.x;
  float acc[8];
#pragma unroll
  for (int u = 0; u < 8; ++u) acc[u] = 0.f;
  for (int k = 0; k < 512; ++k) {
    float w = W2[(size_t)k * 256 + t];
#pragma unroll
    for (int u = 0; u < 8; ++u) acc[u] += h1[(size_t)(r0 + u) * 512 + k] * w;
  }
  float bv = b2[t];
#pragma unroll
  for (int u = 0; u < 8; ++u)
    h2[(size_t)(r0 + u) * 256 + t] = fmaxf(acc[u] + bv, 0.f);
}

// ---------- logits = h2 @ W3 + b3 ----------
__global__ __launch_bounds__(256) void k_mlp3(
    const float* __restrict__ h2, const float* __restrict__ W3,
    const float* __restrict__ b3, float* __restrict__ out) {
  const int r0 = blockIdx.x * 8, t = threadIdx.x;
  const int u = t >> 5, oc = t & 31;
  const float* x = h2 + (size_t)(r0 + u) * 256;
  float acc = 0.f;
  for (int k = 0; k < 256; ++k) acc += x[k] * W3[(size_t)k * 32 + oc];
  out[(size_t)(r0 + u) * 32 + oc] = acc + b3[oc];
}

extern "C" void kernel_launch(void* const* d_in, const int* in_sizes, int n_in,
                              void* d_out, int out_size, void* d_ws, size_t ws_size,
                              hipStream_t stream) {
  const float* x     = (const float*)d_in[0];
  const float* eattr = (const float*)d_in[1];
  const float* W_h   = (const float*)d_in[2];
  const float* b_h   = (const float*)d_in[3];
  const float* Ws_h  = (const float*)d_in[4];
  const float* bs_h  = (const float*)d_in[5];
  const float* Wb    = (const float*)d_in[6];
  const float* bb    = (const float*)d_in[7];
  const float* Wbs   = (const float*)d_in[8];
  const float* bbs   = (const float*)d_in[9];
  const float* W_f   = (const float*)d_in[10];
  const float* b_f   = (const float*)d_in[11];
  const float* W_fs  = (const float*)d_in[12];
  const float* b_fs  = (const float*)d_in[13];
  const float* W1    = (const float*)d_in[14];
  const float* b1    = (const float*)d_in[15];
  const float* W2    = (const float*)d_in[16];
  const float* b2    = (const float*)d_in[17];
  const float* W3    = (const float*)d_in[18];
  const float* b3    = (const float*)d_in[19];
  const int*   edge  = (const int*)d_in[20];
  const int*   bbox  = (const int*)d_in[21];
  float* out = (float*)d_out;

  // ---- workspace layout (~209 MB, unchanged footprint) ----
  float* p = (float*)d_ws;
  float* feats  = p; p += (size_t)NN * FUS;       // 76.8 MB
  float* sfeats = p; p += (size_t)NN * FUS;       // 76.8 MB
  unsigned* Pn = (unsigned*)p;                    // bf16x2 [NN][64] = 12.8 MB
  unsigned* Qn = Pn + (size_t)NN * 64;
  unsigned* Ps = Qn + (size_t)NN * 64;
  unsigned* Qs = Ps + (size_t)NN * 64;
  // overlays (P/Q dead after convs):
  float* pooled = (float*)Pn;                     // 11.26 MB <= 12.8
  float* sb     = (float*)Qn;                     // 0.77 + 2.05 + 1.02 + 0.51
  float* fsup   = sb + (size_t)NB * FUS;
  float* h1     = fsup + (size_t)NB * 1024;
  float* h2     = h1 + (size_t)NB * 512;
  int* eid_arr = (int*)(Qs + (size_t)NN * 64);
  int* row_ptr = eid_arr + NE;
  int* deg     = row_ptr + NN + 1;
  int* cursor  = deg + NN;
  int* seg     = cursor + NN;

  hipMemsetAsync(deg, 0, 2 * NN * sizeof(int), stream);  // deg + cursor

  // ---- CSR build + bbox segments ----
  k_deg<<<(NE + 255) / 256, 256, 0, stream>>>(edge, deg);
  k_scan<<<1, 1024, 0, stream>>>(deg, row_ptr);
  k_fill<<<(NE + 255) / 256, 256, 0, stream>>>(edge, row_ptr, cursor, eid_arr);
  k_segstart<<<(NN + 255) / 256, 256, 0, stream>>>(bbox, seg);

  const int npq_grid = (NN + 31) / 32;

  // ---- conv 0 (head): both streams read x (K=8), one pass ----
  k_node_pq2<<<npq_grid, 256, 0, stream>>>(x, x, INCH, INCH, W_h, b_h, Ws_h, bs_h,
                                           Pn, Qn, Ps, Qs);
  k_conv2<<<NN / 4, 256, 0, stream>>>(row_ptr, eid_arr, edge, eattr, Pn, Qn, Ps, Qs,
                                      W_h + 2 * INCH * CH, Ws_h + 2 * INCH * CH,
                                      feats, sfeats, 0, -1);

  // ---- residual blocks (K=128), one pass per layer ----
  for (int i = 0; i < 2; ++i) {
    const float* Wi  = Wb  + (size_t)i * 262 * CH;
    const float* bi  = bb  + (size_t)i * CH;
    const float* Wsi = Wbs + (size_t)i * 262 * CH;
    const float* bsi = bbs + (size_t)i * CH;
    k_node_pq2<<<npq_grid, 256, 0, stream>>>(feats + i * CH, sfeats + i * CH, FUS, CH,
                                             Wi, bi, Wsi, bsi, Pn, Qn, Ps, Qs);
    k_conv2<<<NN / 4, 256, 0, stream>>>(row_ptr, eid_arr, edge, eattr, Pn, Qn, Ps, Qs,
                                        Wi + 2 * CH * CH, Wsi + 2 * CH * CH,
                                        feats, sfeats, i + 1, i);
  }

  // ---- pooling + MLP head (P/Q dead -> pooled overlay; zero for atomicMax) ----
  hipMemsetAsync(pooled, 0, (size_t)NB * 1408 * sizeof(float), stream);
  k_pool_gemm<<<dim3((NN + 31) / 32, 2), 256, 0, stream>>>(feats, bbox, W_f, b_f,
                                                           pooled);
  k_poolraw<<<NB, 256, 0, stream>>>(feats, sfeats, seg, pooled, sb);
  k_fusion_super<<<NB / 8, 256, 0, stream>>>(sb, W_fs, b_fs, fsup);
  k_mlp1<<<dim3(NB / 8, 2), 256, 0, stream>>>(pooled, fsup, sb, W1, b1, h1);
  k_mlp2<<<NB / 8, 256, 0, stream>>>(h1, W2, b2, h2);
  k_mlp3<<<NB / 8, 256, 0, stream>>>(h2, W3, b3, out);
}

// Round 9
// 2764.920 us; speedup vs baseline: 1.1228x; 1.1228x over previous
//
#include <hip/hip_runtime.h>

#define NN   50000
#define NE   800000
#define INCH 8
#define CH   128
#define EA   6
#define NB   2000
#define NCLS 32
#define FUS  384

// ---------- degree of dst nodes ----------
__global__ __launch_bounds__(256) void k_deg(const int* __restrict__ edge,
                                             int* __restrict__ deg) {
  int e = blockIdx.x * 256 + threadIdx.x;
  if (e < NE) atomicAdd(&deg[edge[NE + e]], 1);
}

// ---------- exclusive scan of deg -> row_ptr (single block, shfl scan) ----------
__global__ __launch_bounds__(1024) void k_scan(const int* __restrict__ deg,
                                               int* __restrict__ row_ptr) {
  __shared__ int wsum[16];
  __shared__ int s_carry;
  const int t = threadIdx.x, lane = t & 63, w = t >> 6;
  if (t == 0) s_carry = 0;
  __syncthreads();
  for (int base = 0; base < NN; base += 1024) {
    int i = base + t;
    int x = (i < NN) ? deg[i] : 0;
#pragma unroll
    for (int off = 1; off < 64; off <<= 1) {
      int y = __shfl_up(x, off, 64);
      if (lane >= off) x += y;
    }
    if (lane == 63) wsum[w] = x;
    __syncthreads();
    if (w == 0 && lane < 16) {
      int s = wsum[lane];
#pragma unroll
      for (int off = 1; off < 16; off <<= 1) {
        int y = __shfl_up(s, off, 64);
        if (lane >= off) s += y;
      }
      wsum[lane] = s;
    }
    __syncthreads();
    int incl = x + ((w == 0) ? 0 : wsum[w - 1]) + s_carry;
    if (i < NN) row_ptr[i + 1] = incl;
    __syncthreads();
    if (t == 1023) s_carry = incl;
    __syncthreads();
  }
  if (t == 0) row_ptr[0] = 0;
}

// ---------- fill CSR: edge ids grouped by dst ----------
__global__ __launch_bounds__(256) void k_fill(
    const int* __restrict__ edge, const int* __restrict__ row_ptr,
    int* __restrict__ cursor, int* __restrict__ eid_arr) {
  int e = blockIdx.x * 256 + threadIdx.x;
  if (e >= NE) return;
  int d = edge[NE + e];
  int idx = row_ptr[d] + atomicAdd(&cursor[d], 1);
  eid_arr[idx] = e;
}

// ---------- segment starts from sorted bbox_idx ----------
__global__ __launch_bounds__(256) void k_segstart(const int* __restrict__ bbox,
                                                  int* __restrict__ seg) {
  int i = blockIdx.x * 256 + threadIdx.x;
  if (i >= NN) return;
  int bc = bbox[i];
  int bp = (i == 0) ? -1 : bbox[i - 1];
  for (int j = bp + 1; j <= bc; ++j) seg[j] = i;
  if (i == NN - 1)
    for (int j = bc + 1; j <= NB; ++j) seg[j] = NN;
}

// ---------- node transform: P = X@(W1-W2)+b, Q = X@W2 ----------
// Block = 4 waves x 8 nodes. Lane-distributed x (8 nodes x 8 k per load),
// consumed via static __shfl (v_readlane -> SGPR FMA operand).
__global__ __launch_bounds__(256) void k_node_pq(
    const float* __restrict__ X, int ldx, int K,
    const float* __restrict__ W, const float* __restrict__ bias,
    float* __restrict__ P, float* __restrict__ Q) {
  const int t = threadIdx.x, lane = t & 63, wv = t >> 6;
  const int nbase = blockIdx.x * 32 + wv * 8;
  const int c = lane * 2;
  const float2 bv = *(const float2*)(bias + c);
  float2 pacc[8], qacc[8];
#pragma unroll
  for (int u = 0; u < 8; ++u) { pacc[u] = bv; qacc[u] = make_float2(0.f, 0.f); }
  const int xrow = min(nbase + (lane >> 3), NN - 1);
  const int xk = lane & 7;
  for (int k0 = 0; k0 < K; k0 += 8) {
    const float xv = X[(size_t)xrow * ldx + k0 + xk];
#pragma unroll
    for (int j = 0; j < 8; ++j) {
      const float2 w1 = *(const float2*)(W + (size_t)(k0 + j) * CH + c);
      const float2 w2 = *(const float2*)(W + (size_t)(K + k0 + j) * CH + c);
      const float2 wd = {w1.x - w2.x, w1.y - w2.y};
#pragma unroll
      for (int u = 0; u < 8; ++u) {
        const float xs = __shfl(xv, u * 8 + j, 64);
        pacc[u].x += xs * wd.x; pacc[u].y += xs * wd.y;
        qacc[u].x += xs * w2.x; qacc[u].y += xs * w2.y;
      }
    }
  }
#pragma unroll
  for (int u = 0; u < 8; ++u) {
    const int node = nbase + u;
    if (node < NN) {
      *(float2*)(P + (size_t)node * CH + c) = pacc[u];
      *(float2*)(Q + (size_t)node * CH + c) = qacc[u];
    }
  }
}

// ---------- CSR conv: one node per WAVE, lane-batched edge meta + shfl ----------
template <int MODE>  // 0 = max, 1 = mean
__global__ __launch_bounds__(256) void k_conv(
    const int* __restrict__ row_ptr, const int* __restrict__ eid_arr,
    const int* __restrict__ edge, const float* __restrict__ eattr,
    const float* __restrict__ P, const float* __restrict__ Q,
    const float* __restrict__ C, float* __restrict__ outf,
    int cur, int prev) {
  const int t = threadIdx.x;
  const int lane = t & 63;
  const int node = blockIdx.x * 4 + (t >> 6);
  const int c = lane * 2;
  float2 cw[EA];
#pragma unroll
  for (int j = 0; j < EA; ++j) cw[j] = *(const float2*)(C + j * CH + c);
  int i0 = __builtin_amdgcn_readfirstlane(row_ptr[node]);
  int i1 = __builtin_amdgcn_readfirstlane(row_ptr[node + 1]);
  const float2 q = *(const float2*)(Q + (size_t)node * CH + c);
  float a0 = 0.f, a1 = 0.f;
  for (int base = i0; base < i1; base += 64) {
    const int cnt = min(64, i1 - base);
    int s_l = 0;
    float ea0 = 0.f, ea1 = 0.f, ea2 = 0.f, ea3 = 0.f, ea4 = 0.f, ea5 = 0.f;
    if (lane < cnt) {
      int e = eid_arr[base + lane];      // coalesced
      s_l = edge[e];                     // gather
      const float* ep = eattr + (size_t)e * EA;
      ea0 = ep[0]; ea1 = ep[1]; ea2 = ep[2];
      ea3 = ep[3]; ea4 = ep[4]; ea5 = ep[5];
    }
#define EDGE_BODY(J)                                                       \
    {                                                                      \
      int s = __shfl(s_l, (J), 64);                                        \
      float e0 = __shfl(ea0, (J), 64), e1 = __shfl(ea1, (J), 64);          \
      float e2 = __shfl(ea2, (J), 64), e3 = __shfl(ea3, (J), 64);          \
      float e4 = __shfl(ea4, (J), 64), e5 = __shfl(ea5, (J), 64);          \
      const float2 pv = *(const float2*)(P + (size_t)s * CH + c);          \
      float v0 = pv.x + q.x, v1 = pv.y + q.y;                              \
      v0 += e0 * cw[0].x; v1 += e0 * cw[0].y;                              \
      v0 += e1 * cw[1].x; v1 += e1 * cw[1].y;                              \
      v0 += e2 * cw[2].x; v1 += e2 * cw[2].y;                              \
      v0 += e3 * cw[3].x; v1 += e3 * cw[3].y;                              \
      v0 += e4 * cw[4].x; v1 += e4 * cw[4].y;                              \
      v0 += e5 * cw[5].x; v1 += e5 * cw[5].y;                              \
      if (MODE == 0) { a0 = fmaxf(a0, v0); a1 = fmaxf(a1, v1); }           \
      else           { a0 += fmaxf(v0, 0.f); a1 += fmaxf(v1, 0.f); }       \
    }
    int j = 0;
    for (; j + 4 <= cnt; j += 4) {
      EDGE_BODY(j) EDGE_BODY(j + 1) EDGE_BODY(j + 2) EDGE_BODY(j + 3)
    }
    for (; j < cnt; ++j) EDGE_BODY(j)
#undef EDGE_BODY
  }
  if (MODE == 1) {
    float inv = 1.f / fmaxf((float)(i1 - i0), 1.f);
    a0 *= inv; a1 *= inv;
  }
  size_t o = (size_t)node * FUS + (size_t)cur * CH + c;
  if (prev >= 0) {
    const float2 pr = *(const float2*)(outf + (size_t)node * FUS + (size_t)prev * CH + c);
    a0 += pr.x; a1 += pr.y;
  }
  float2 ov = {a0, a1};
  *(float2*)(outf + o) = ov;
}

// ---------- fusion GEMM over ALL nodes + segment max via atomicMax ----------
// Dense tiles: 64 nodes x 512 cols per block (4 waves x 16 nodes, thread owns
// 8 cols, acc[16][8]). Per j-step: 2 W loads (L1-shared across waves) feed
// 256 FMA-cycles/wave -> load latency fully hidden (R7 was 128 -> 50% VALU).
// Nodes bbox-sorted: thread run-merges its 16 nodes by bbox id, one atomicMax
// per (bbox,col). relu>=0 + pooled pre-zeroed -> uint max == float max.
__global__ __launch_bounds__(256) void k_pool_gemm(
    const float* __restrict__ feats, const int* __restrict__ bbox,
    const float* __restrict__ Wf, const float* __restrict__ bf,
    float* __restrict__ pooled) {
  const int t = threadIdx.x, lane = t & 63, wv = t >> 6;
  const int nbase = blockIdx.x * 64 + wv * 16;
  const int col0 = blockIdx.y * 512 + lane * 8;
  float acc[16][8];
#pragma unroll
  for (int u = 0; u < 16; ++u)
#pragma unroll
    for (int i = 0; i < 8; ++i) acc[u][i] = 0.f;
  const int xr0 = min(nbase + (lane >> 3), NN - 1);
  const int xr1 = min(nbase + 8 + (lane >> 3), NN - 1);
  const int xk = lane & 7;
  for (int k0 = 0; k0 < FUS; k0 += 8) {
    const float xv0 = feats[(size_t)xr0 * FUS + k0 + xk];
    const float xv1 = feats[(size_t)xr1 * FUS + k0 + xk];
#pragma unroll
    for (int j = 0; j < 8; ++j) {
      const float4 w0 = *(const float4*)(Wf + (size_t)(k0 + j) * 1024 + col0);
      const float4 w1 = *(const float4*)(Wf + (size_t)(k0 + j) * 1024 + col0 + 4);
#pragma unroll
      for (int u = 0; u < 8; ++u) {
        const float xs = __shfl(xv0, u * 8 + j, 64);
        acc[u][0] += xs * w0.x; acc[u][1] += xs * w0.y;
        acc[u][2] += xs * w0.z; acc[u][3] += xs * w0.w;
        acc[u][4] += xs * w1.x; acc[u][5] += xs * w1.y;
        acc[u][6] += xs * w1.z; acc[u][7] += xs * w1.w;
      }
#pragma unroll
      for (int u = 0; u < 8; ++u) {
        const float xs = __shfl(xv1, u * 8 + j, 64);
        acc[8 + u][0] += xs * w0.x; acc[8 + u][1] += xs * w0.y;
        acc[8 + u][2] += xs * w0.z; acc[8 + u][3] += xs * w0.w;
        acc[8 + u][4] += xs * w1.x; acc[8 + u][5] += xs * w1.y;
        acc[8 + u][6] += xs * w1.z; acc[8 + u][7] += xs * w1.w;
      }
    }
  }
  // epilogue: bias + relu, run-merge by bbox id (ascending), atomicMax
  float b8[8];
  *(float4*)&b8[0] = *(const float4*)(bf + col0);
  *(float4*)&b8[4] = *(const float4*)(bf + col0 + 4);
  int curb = -1;
  float m[8];
#pragma unroll
  for (int i = 0; i < 8; ++i) m[i] = 0.f;
#pragma unroll
  for (int u = 0; u < 16; ++u) {
    const int node = nbase + u;
    if (node < NN) {                      // wave-uniform guard
      const int bid = bbox[node];
      float v[8];
#pragma unroll
      for (int i = 0; i < 8; ++i) v[i] = fmaxf(acc[u][i] + b8[i], 0.f);
      if (bid != curb) {
        if (curb >= 0) {
#pragma unroll
          for (int i = 0; i < 8; ++i)
            atomicMax((unsigned int*)(pooled + (size_t)curb * 1408 + col0 + i),
                      __float_as_uint(m[i]));
        }
        curb = bid;
#pragma unroll
        for (int i = 0; i < 8; ++i) m[i] = v[i];
      } else {
#pragma unroll
        for (int i = 0; i < 8; ++i) m[i] = fmaxf(m[i], v[i]);
      }
    }
  }
  if (curb >= 0) {
#pragma unroll
    for (int i = 0; i < 8; ++i)
      atomicMax((unsigned int*)(pooled + (size_t)curb * 1408 + col0 + i),
                __float_as_uint(m[i]));
  }
}

// ---------- raw-feats bbox max + sfeats bbox mean ----------
__global__ __launch_bounds__(256) void k_poolraw(
    const float* __restrict__ feats, const float* __restrict__ sfeats,
    const int* __restrict__ seg, float* __restrict__ pooled,
    float* __restrict__ sb) {
  const int b = blockIdx.x, t = threadIdx.x;
  if (t >= 192) return;
  const int c2 = t * 2;
  const int n0 = __builtin_amdgcn_readfirstlane(seg[b]);
  const int n1 = __builtin_amdgcn_readfirstlane(seg[b + 1]);
  float2 fmx = {0.f, 0.f}, ss = {0.f, 0.f};
  for (int n = n0; n < n1; ++n) {
    const float2 f2 = *(const float2*)(feats + (size_t)n * FUS + c2);
    fmx.x = fmaxf(fmx.x, f2.x); fmx.y = fmaxf(fmx.y, f2.y);
    const float2 s2 = *(const float2*)(sfeats + (size_t)n * FUS + c2);
    ss.x += s2.x; ss.y += s2.y;
  }
  *(float2*)(pooled + (size_t)b * 1408 + 1024 + c2) = fmx;
  const float inv = 1.f / fmaxf((float)(n1 - n0), 1.f);
  float2 o = {ss.x * inv, ss.y * inv};
  *(float2*)(sb + (size_t)b * FUS + c2) = o;
}

// ---------- fusion_super = relu(sb @ Wfs + bfs) ----------
__global__ __launch_bounds__(256) void k_fusion_super(
    const float* __restrict__ sb, const float* __restrict__ Wfs,
    const float* __restrict__ bfs, float* __restrict__ fs) {
  const int r0 = blockIdx.x * 8, t = threadIdx.x;
  float acc[8][4];
#pragma unroll
  for (int u = 0; u < 8; ++u)
    acc[u][0] = acc[u][1] = acc[u][2] = acc[u][3] = 0.f;
  for (int k = 0; k < FUS; ++k) {
    const float4 w = *(const float4*)(Wfs + (size_t)k * 1024 + t * 4);
#pragma unroll
    for (int u = 0; u < 8; ++u) {
      float x = sb[(size_t)(r0 + u) * FUS + k];
      acc[u][0] += x * w.x; acc[u][1] += x * w.y;
      acc[u][2] += x * w.z; acc[u][3] += x * w.w;
    }
  }
  const float4 b4 = *(const float4*)(bfs + t * 4);
#pragma unroll
  for (int u = 0; u < 8; ++u) {
    float4 o = {fmaxf(acc[u][0] + b4.x, 0.f), fmaxf(acc[u][1] + b4.y, 0.f),
                fmaxf(acc[u][2] + b4.z, 0.f), fmaxf(acc[u][3] + b4.w, 0.f)};
    *(float4*)(fs + (size_t)(r0 + u) * 1024 + t * 4) = o;
  }
}

// ---------- h1 = relu(concat(pooled, fs, sb) @ W1 + b1), column-split ----------
__global__ __launch_bounds__(256) void k_mlp1(
    const float* __restrict__ pooled, const float* __restrict__ fs,
    const float* __restrict__ sb, const float* __restrict__ W1,
    const float* __restrict__ b1, float* __restrict__ h1) {
  const int r0 = blockIdx.x * 8;
  const int col = blockIdx.y * 256 + threadIdx.x;
  float acc[8];
#pragma unroll
  for (int u = 0; u < 8; ++u) acc[u] = 0.f;
  for (int k = 0; k < 1408; ++k) {
    float w = W1[(size_t)k * 512 + col];
#pragma unroll
    for (int u = 0; u < 8; ++u) acc[u] += pooled[(size_t)(r0 + u) * 1408 + k] * w;
  }
  for (int k = 0; k < 1024; ++k) {
    float w = W1[(size_t)(1408 + k) * 512 + col];
#pragma unroll
    for (int u = 0; u < 8; ++u) acc[u] += fs[(size_t)(r0 + u) * 1024 + k] * w;
  }
  for (int k = 0; k < FUS; ++k) {
    float w = W1[(size_t)(2432 + k) * 512 + col];
#pragma unroll
    for (int u = 0; u < 8; ++u) acc[u] += sb[(size_t)(r0 + u) * FUS + k] * w;
  }
  float bv = b1[col];
#pragma unroll
  for (int u = 0; u < 8; ++u)
    h1[(size_t)(r0 + u) * 512 + col] = fmaxf(acc[u] + bv, 0.f);
}

// ---------- h2 = relu(h1 @ W2 + b2) ----------
__global__ __launch_bounds__(256) void k_mlp2(
    const float* __restrict__ h1, const float* __restrict__ W2,
    const float* __restrict__ b2, float* __restrict__ h2) {
  const int r0 = blockIdx.x * 8, t = threadIdx.x;
  float acc[8];
#pragma unroll
  for (int u = 0; u < 8; ++u) acc[u] = 0.f;
  for (int k = 0; k < 512; ++k) {
    float w = W2[(size_t)k * 256 + t];
#pragma unroll
    for (int u = 0; u < 8; ++u) acc[u] += h1[(size_t)(r0 + u) * 512 + k] * w;
  }
  float bv = b2[t];
#pragma unroll
  for (int u = 0; u < 8; ++u)
    h2[(size_t)(r0 + u) * 256 + t] = fmaxf(acc[u] + bv, 0.f);
}

// ---------- logits = h2 @ W3 + b3 ----------
__global__ __launch_bounds__(256) void k_mlp3(
    const float* __restrict__ h2, const float* __restrict__ W3,
    const float* __restrict__ b3, float* __restrict__ out) {
  const int r0 = blockIdx.x * 8, t = threadIdx.x;
  const int u = t >> 5, oc = t & 31;
  const float* x = h2 + (size_t)(r0 + u) * 256;
  float acc = 0.f;
  for (int k = 0; k < 256; ++k) acc += x[k] * W3[(size_t)k * 32 + oc];
  out[(size_t)(r0 + u) * 32 + oc] = acc + b3[oc];
}

extern "C" void kernel_launch(void* const* d_in, const int* in_sizes, int n_in,
                              void* d_out, int out_size, void* d_ws, size_t ws_size,
                              hipStream_t stream) {
  const float* x     = (const float*)d_in[0];
  const float* eattr = (const float*)d_in[1];
  const float* W_h   = (const float*)d_in[2];
  const float* b_h   = (const float*)d_in[3];
  const float* Ws_h  = (const float*)d_in[4];
  const float* bs_h  = (const float*)d_in[5];
  const float* Wb    = (const float*)d_in[6];
  const float* bb    = (const float*)d_in[7];
  const float* Wbs   = (const float*)d_in[8];
  const float* bbs   = (const float*)d_in[9];
  const float* W_f   = (const float*)d_in[10];
  const float* b_f   = (const float*)d_in[11];
  const float* W_fs  = (const float*)d_in[12];
  const float* b_fs  = (const float*)d_in[13];
  const float* W1    = (const float*)d_in[14];
  const float* b1    = (const float*)d_in[15];
  const float* W2    = (const float*)d_in[16];
  const float* b2    = (const float*)d_in[17];
  const float* W3    = (const float*)d_in[18];
  const float* b3    = (const float*)d_in[19];
  const int*   edge  = (const int*)d_in[20];
  const int*   bbox  = (const int*)d_in[21];
  float* out = (float*)d_out;

  // ---- workspace layout (~209 MB) ----
  float* p = (float*)d_ws;
  float* feats  = p; p += (size_t)NN * FUS;
  float* sfeats = p; p += (size_t)NN * FUS;
  float* P      = p; p += (size_t)NN * CH;
  float* Q      = p; p += (size_t)NN * CH;
  float* sb     = P;                         // overlap: dead after convs
  float* fsup   = P + (size_t)NB * FUS;
  float* h1     = fsup + (size_t)NB * 1024;
  float* h2     = h1 + (size_t)NB * 512;
  float* pooled = Q;
  int* eid_arr = (int*)p;
  int* row_ptr = eid_arr + NE;
  int* deg     = row_ptr + NN + 1;
  int* cursor  = deg + NN;
  int* seg     = cursor + NN;

  hipMemsetAsync(deg, 0, 2 * NN * sizeof(int), stream);  // deg + cursor

  // ---- CSR build + bbox segments ----
  k_deg<<<(NE + 255) / 256, 256, 0, stream>>>(edge, deg);
  k_scan<<<1, 1024, 0, stream>>>(deg, row_ptr);
  k_fill<<<(NE + 255) / 256, 256, 0, stream>>>(edge, row_ptr, cursor, eid_arr);
  k_segstart<<<(NN + 255) / 256, 256, 0, stream>>>(bbox, seg);

  const int npq_grid = (NN + 31) / 32;

  // ---- conv 0 (head): both streams read x (K=8) ----
  k_node_pq<<<npq_grid, 256, 0, stream>>>(x, INCH, INCH, W_h, b_h, P, Q);
  k_conv<0><<<NN / 4, 256, 0, stream>>>(row_ptr, eid_arr, edge, eattr, P, Q,
                                        W_h + 2 * INCH * CH, feats, 0, -1);
  k_node_pq<<<npq_grid, 256, 0, stream>>>(x, INCH, INCH, Ws_h, bs_h, P, Q);
  k_conv<1><<<NN / 4, 256, 0, stream>>>(row_ptr, eid_arr, edge, eattr, P, Q,
                                        Ws_h + 2 * INCH * CH, sfeats, 0, -1);

  // ---- residual blocks (K=128) ----
  for (int i = 0; i < 2; ++i) {
    const float* Wi  = Wb  + (size_t)i * 262 * CH;
    const float* bi  = bb  + (size_t)i * CH;
    const float* Wsi = Wbs + (size_t)i * 262 * CH;
    const float* bsi = bbs + (size_t)i * CH;
    k_node_pq<<<npq_grid, 256, 0, stream>>>(feats + i * CH, FUS, CH, Wi, bi, P, Q);
    k_conv<0><<<NN / 4, 256, 0, stream>>>(row_ptr, eid_arr, edge, eattr, P, Q,
                                          Wi + 2 * CH * CH, feats, i + 1, i);
    k_node_pq<<<npq_grid, 256, 0, stream>>>(sfeats + i * CH, FUS, CH, Wsi, bsi, P, Q);
    k_conv<1><<<NN / 4, 256, 0, stream>>>(row_ptr, eid_arr, edge, eattr, P, Q,
                                          Wsi + 2 * CH * CH, sfeats, i + 1, i);
  }

  // ---- pooling + MLP head (Q dead -> becomes pooled; zero for atomicMax) ----
  hipMemsetAsync(pooled, 0, (size_t)NB * 1408 * sizeof(float), stream);
  k_pool_gemm<<<dim3((NN + 63) / 64, 2), 256, 0, stream>>>(feats, bbox, W_f, b_f,
                                                           pooled);
  k_poolraw<<<NB, 256, 0, stream>>>(feats, sfeats, seg, pooled, sb);
  k_fusion_super<<<NB / 8, 256, 0, stream>>>(sb, W_fs, b_fs, fsup);
  k_mlp1<<<dim3(NB / 8, 2), 256, 0, stream>>>(pooled, fsup, sb, W1, b1, h1);
  k_mlp2<<<NB / 8, 256, 0, stream>>>(h1, W2, b2, h2);
  k_mlp3<<<NB / 8, 256, 0, stream>>>(h2, W3, b3, out);
}

// Round 10
// 2736.110 us; speedup vs baseline: 1.1346x; 1.0105x over previous
//
#include <hip/hip_runtime.h>

#define NN   50000
#define NE   800000
#define INCH 8
#define CH   128
#define EA   6
#define NB   2000
#define NCLS 32
#define FUS  384

// ---------- degree of dst nodes ----------
__global__ __launch_bounds__(256) void k_deg(const int* __restrict__ edge,
                                             int* __restrict__ deg) {
  int e = blockIdx.x * 256 + threadIdx.x;
  if (e < NE) atomicAdd(&deg[edge[NE + e]], 1);
}

// ---------- exclusive scan of deg -> row_ptr (single block, shfl scan) ----------
__global__ __launch_bounds__(1024) void k_scan(const int* __restrict__ deg,
                                               int* __restrict__ row_ptr) {
  __shared__ int wsum[16];
  __shared__ int s_carry;
  const int t = threadIdx.x, lane = t & 63, w = t >> 6;
  if (t == 0) s_carry = 0;
  __syncthreads();
  for (int base = 0; base < NN; base += 1024) {
    int i = base + t;
    int x = (i < NN) ? deg[i] : 0;
#pragma unroll
    for (int off = 1; off < 64; off <<= 1) {
      int y = __shfl_up(x, off, 64);
      if (lane >= off) x += y;
    }
    if (lane == 63) wsum[w] = x;
    __syncthreads();
    if (w == 0 && lane < 16) {
      int s = wsum[lane];
#pragma unroll
      for (int off = 1; off < 16; off <<= 1) {
        int y = __shfl_up(s, off, 64);
        if (lane >= off) s += y;
      }
      wsum[lane] = s;
    }
    __syncthreads();
    int incl = x + ((w == 0) ? 0 : wsum[w - 1]) + s_carry;
    if (i < NN) row_ptr[i + 1] = incl;
    __syncthreads();
    if (t == 1023) s_carry = incl;
    __syncthreads();
  }
  if (t == 0) row_ptr[0] = 0;
}

// ---------- fill CSR: edge ids grouped by dst ----------
__global__ __launch_bounds__(256) void k_fill(
    const int* __restrict__ edge, const int* __restrict__ row_ptr,
    int* __restrict__ cursor, int* __restrict__ eid_arr) {
  int e = blockIdx.x * 256 + threadIdx.x;
  if (e >= NE) return;
  int d = edge[NE + e];
  int idx = row_ptr[d] + atomicAdd(&cursor[d], 1);
  eid_arr[idx] = e;
}

// ---------- segment starts from sorted bbox_idx ----------
__global__ __launch_bounds__(256) void k_segstart(const int* __restrict__ bbox,
                                                  int* __restrict__ seg) {
  int i = blockIdx.x * 256 + threadIdx.x;
  if (i >= NN) return;
  int bc = bbox[i];
  int bp = (i == 0) ? -1 : bbox[i - 1];
  for (int j = bp + 1; j <= bc; ++j) seg[j] = i;
  if (i == NN - 1)
    for (int j = bc + 1; j <= NB; ++j) seg[j] = NN;
}

// ---------- node transform: P = X@(W1-W2)+b, Q = X@W2 ----------
// Block = 4 waves x 8 nodes. Lane-distributed x (8 nodes x 8 k per load),
// consumed via static __shfl (v_readlane -> SGPR FMA operand).
__global__ __launch_bounds__(256) void k_node_pq(
    const float* __restrict__ X, int ldx, int K,
    const float* __restrict__ W, const float* __restrict__ bias,
    float* __restrict__ P, float* __restrict__ Q) {
  const int t = threadIdx.x, lane = t & 63, wv = t >> 6;
  const int nbase = blockIdx.x * 32 + wv * 8;
  const int c = lane * 2;
  const float2 bv = *(const float2*)(bias + c);
  float2 pacc[8], qacc[8];
#pragma unroll
  for (int u = 0; u < 8; ++u) { pacc[u] = bv; qacc[u] = make_float2(0.f, 0.f); }
  const int xrow = min(nbase + (lane >> 3), NN - 1);
  const int xk = lane & 7;
  for (int k0 = 0; k0 < K; k0 += 8) {
    const float xv = X[(size_t)xrow * ldx + k0 + xk];
#pragma unroll
    for (int j = 0; j < 8; ++j) {
      const float2 w1 = *(const float2*)(W + (size_t)(k0 + j) * CH + c);
      const float2 w2 = *(const float2*)(W + (size_t)(K + k0 + j) * CH + c);
      const float2 wd = {w1.x - w2.x, w1.y - w2.y};
#pragma unroll
      for (int u = 0; u < 8; ++u) {
        const float xs = __shfl(xv, u * 8 + j, 64);
        pacc[u].x += xs * wd.x; pacc[u].y += xs * wd.y;
        qacc[u].x += xs * w2.x; qacc[u].y += xs * w2.y;
      }
    }
  }
#pragma unroll
  for (int u = 0; u < 8; ++u) {
    const int node = nbase + u;
    if (node < NN) {
      *(float2*)(P + (size_t)node * CH + c) = pacc[u];
      *(float2*)(Q + (size_t)node * CH + c) = qacc[u];
    }
  }
}

// ---------- CSR conv: one node per WAVE, lane-batched edge meta + shfl ----------
template <int MODE>  // 0 = max, 1 = mean
__global__ __launch_bounds__(256) void k_conv(
    const int* __restrict__ row_ptr, const int* __restrict__ eid_arr,
    const int* __restrict__ edge, const float* __restrict__ eattr,
    const float* __restrict__ P, const float* __restrict__ Q,
    const float* __restrict__ C, float* __restrict__ outf,
    int cur, int prev) {
  const int t = threadIdx.x;
  const int lane = t & 63;
  const int node = blockIdx.x * 4 + (t >> 6);
  const int c = lane * 2;
  float2 cw[EA];
#pragma unroll
  for (int j = 0; j < EA; ++j) cw[j] = *(const float2*)(C + j * CH + c);
  int i0 = __builtin_amdgcn_readfirstlane(row_ptr[node]);
  int i1 = __builtin_amdgcn_readfirstlane(row_ptr[node + 1]);
  const float2 q = *(const float2*)(Q + (size_t)node * CH + c);
  float a0 = 0.f, a1 = 0.f;
  for (int base = i0; base < i1; base += 64) {
    const int cnt = min(64, i1 - base);
    int s_l = 0;
    float ea0 = 0.f, ea1 = 0.f, ea2 = 0.f, ea3 = 0.f, ea4 = 0.f, ea5 = 0.f;
    if (lane < cnt) {
      int e = eid_arr[base + lane];      // coalesced
      s_l = edge[e];                     // gather
      const float* ep = eattr + (size_t)e * EA;
      ea0 = ep[0]; ea1 = ep[1]; ea2 = ep[2];
      ea3 = ep[3]; ea4 = ep[4]; ea5 = ep[5];
    }
#define EDGE_BODY(J)                                                       \
    {                                                                      \
      int s = __shfl(s_l, (J), 64);                                        \
      float e0 = __shfl(ea0, (J), 64), e1 = __shfl(ea1, (J), 64);          \
      float e2 = __shfl(ea2, (J), 64), e3 = __shfl(ea3, (J), 64);          \
      float e4 = __shfl(ea4, (J), 64), e5 = __shfl(ea5, (J), 64);          \
      const float2 pv = *(const float2*)(P + (size_t)s * CH + c);          \
      float v0 = pv.x + q.x, v1 = pv.y + q.y;                              \
      v0 += e0 * cw[0].x; v1 += e0 * cw[0].y;                              \
      v0 += e1 * cw[1].x; v1 += e1 * cw[1].y;                              \
      v0 += e2 * cw[2].x; v1 += e2 * cw[2].y;                              \
      v0 += e3 * cw[3].x; v1 += e3 * cw[3].y;                              \
      v0 += e4 * cw[4].x; v1 += e4 * cw[4].y;                              \
      v0 += e5 * cw[5].x; v1 += e5 * cw[5].y;                              \
      if (MODE == 0) { a0 = fmaxf(a0, v0); a1 = fmaxf(a1, v1); }           \
      else           { a0 += fmaxf(v0, 0.f); a1 += fmaxf(v1, 0.f); }       \
    }
    int j = 0;
    for (; j + 8 <= cnt; j += 8) {
      EDGE_BODY(j)     EDGE_BODY(j + 1) EDGE_BODY(j + 2) EDGE_BODY(j + 3)
      EDGE_BODY(j + 4) EDGE_BODY(j + 5) EDGE_BODY(j + 6) EDGE_BODY(j + 7)
    }
    for (; j < cnt; ++j) EDGE_BODY(j)
#undef EDGE_BODY
  }
  if (MODE == 1) {
    float inv = 1.f / fmaxf((float)(i1 - i0), 1.f);
    a0 *= inv; a1 *= inv;
  }
  size_t o = (size_t)node * FUS + (size_t)cur * CH + c;
  if (prev >= 0) {
    const float2 pr = *(const float2*)(outf + (size_t)node * FUS + (size_t)prev * CH + c);
    a0 += pr.x; a1 += pr.y;
  }
  float2 ov = {a0, a1};
  *(float2*)(outf + o) = ov;
}

// ---------- fusion GEMM over ALL nodes + segment max via atomicMax ----------
// Tiles: 32 nodes x 256 cols per block (4 waves x 8 nodes; thread owns 4 cols,
// acc[8][4] ~ 50 VGPR -> 8 waves/SIMD for latency hiding; R9's acc[16][8]
// spilled, R7's acc[8][8] sat at 2.5 waves/SIMD & 50% VALU).
// Nodes bbox-sorted: thread run-merges its 8 nodes by bbox id, one atomicMax
// per (bbox,col). relu>=0 + pooled pre-zeroed -> uint max == float max.
__global__ __launch_bounds__(256) void k_pool_gemm(
    const float* __restrict__ feats, const int* __restrict__ bbox,
    const float* __restrict__ Wf, const float* __restrict__ bf,
    float* __restrict__ pooled) {
  const int t = threadIdx.x, lane = t & 63, wv = t >> 6;
  const int nbase = blockIdx.x * 32 + wv * 8;
  const int col0 = blockIdx.y * 256 + lane * 4;
  float acc[8][4];
#pragma unroll
  for (int u = 0; u < 8; ++u)
#pragma unroll
    for (int i = 0; i < 4; ++i) acc[u][i] = 0.f;
  const int xrow = min(nbase + (lane >> 3), NN - 1);
  const int xk = lane & 7;
  for (int k0 = 0; k0 < FUS; k0 += 8) {
    const float xv = feats[(size_t)xrow * FUS + k0 + xk];
#pragma unroll
    for (int j = 0; j < 8; ++j) {
      const float4 w = *(const float4*)(Wf + (size_t)(k0 + j) * 1024 + col0);
#pragma unroll
      for (int u = 0; u < 8; ++u) {
        const float xs = __shfl(xv, u * 8 + j, 64);
        acc[u][0] += xs * w.x; acc[u][1] += xs * w.y;
        acc[u][2] += xs * w.z; acc[u][3] += xs * w.w;
      }
    }
  }
  // epilogue: bias + relu, run-merge by bbox id (ascending), atomicMax
  float4 b4 = *(const float4*)(bf + col0);
  float b8[4] = {b4.x, b4.y, b4.z, b4.w};
  int curb = -1;
  float m[4];
#pragma unroll
  for (int i = 0; i < 4; ++i) m[i] = 0.f;
#pragma unroll
  for (int u = 0; u < 8; ++u) {
    const int node = nbase + u;
    if (node < NN) {                      // wave-uniform guard
      const int bid = bbox[node];
      float v[4];
#pragma unroll
      for (int i = 0; i < 4; ++i) v[i] = fmaxf(acc[u][i] + b8[i], 0.f);
      if (bid != curb) {
        if (curb >= 0) {
#pragma unroll
          for (int i = 0; i < 4; ++i)
            atomicMax((unsigned int*)(pooled + (size_t)curb * 1408 + col0 + i),
                      __float_as_uint(m[i]));
        }
        curb = bid;
#pragma unroll
        for (int i = 0; i < 4; ++i) m[i] = v[i];
      } else {
#pragma unroll
        for (int i = 0; i < 4; ++i) m[i] = fmaxf(m[i], v[i]);
      }
    }
  }
  if (curb >= 0) {
#pragma unroll
    for (int i = 0; i < 4; ++i)
      atomicMax((unsigned int*)(pooled + (size_t)curb * 1408 + col0 + i),
                __float_as_uint(m[i]));
  }
}

// ---------- raw-feats bbox max + sfeats bbox mean ----------
__global__ __launch_bounds__(256) void k_poolraw(
    const float* __restrict__ feats, const float* __restrict__ sfeats,
    const int* __restrict__ seg, float* __restrict__ pooled,
    float* __restrict__ sb) {
  const int b = blockIdx.x, t = threadIdx.x;
  if (t >= 192) return;
  const int c2 = t * 2;
  const int n0 = __builtin_amdgcn_readfirstlane(seg[b]);
  const int n1 = __builtin_amdgcn_readfirstlane(seg[b + 1]);
  float2 fmx = {0.f, 0.f}, ss = {0.f, 0.f};
  for (int n = n0; n < n1; ++n) {
    const float2 f2 = *(const float2*)(feats + (size_t)n * FUS + c2);
    fmx.x = fmaxf(fmx.x, f2.x); fmx.y = fmaxf(fmx.y, f2.y);
    const float2 s2 = *(const float2*)(sfeats + (size_t)n * FUS + c2);
    ss.x += s2.x; ss.y += s2.y;
  }
  *(float2*)(pooled + (size_t)b * 1408 + 1024 + c2) = fmx;
  const float inv = 1.f / fmaxf((float)(n1 - n0), 1.f);
  float2 o = {ss.x * inv, ss.y * inv};
  *(float2*)(sb + (size_t)b * FUS + c2) = o;
}

// ---------- fusion_super = relu(sb @ Wfs + bfs) ----------
__global__ __launch_bounds__(256) void k_fusion_super(
    const float* __restrict__ sb, const float* __restrict__ Wfs,
    const float* __restrict__ bfs, float* __restrict__ fs) {
  const int r0 = blockIdx.x * 8, t = threadIdx.x;
  float acc[8][4];
#pragma unroll
  for (int u = 0; u < 8; ++u)
    acc[u][0] = acc[u][1] = acc[u][2] = acc[u][3] = 0.f;
  for (int k = 0; k < FUS; ++k) {
    const float4 w = *(const float4*)(Wfs + (size_t)k * 1024 + t * 4);
#pragma unroll
    for (int u = 0; u < 8; ++u) {
      float x = sb[(size_t)(r0 + u) * FUS + k];
      acc[u][0] += x * w.x; acc[u][1] += x * w.y;
      acc[u][2] += x * w.z; acc[u][3] += x * w.w;
    }
  }
  const float4 b4 = *(const float4*)(bfs + t * 4);
#pragma unroll
  for (int u = 0; u < 8; ++u) {
    float4 o = {fmaxf(acc[u][0] + b4.x, 0.f), fmaxf(acc[u][1] + b4.y, 0.f),
                fmaxf(acc[u][2] + b4.z, 0.f), fmaxf(acc[u][3] + b4.w, 0.f)};
    *(float4*)(fs + (size_t)(r0 + u) * 1024 + t * 4) = o;
  }
}

// ---------- h1 = relu(concat(pooled, fs, sb) @ W1 + b1), column-split ----------
__global__ __launch_bounds__(256) void k_mlp1(
    const float* __restrict__ pooled, const float* __restrict__ fs,
    const float* __restrict__ sb, const float* __restrict__ W1,
    const float* __restrict__ b1, float* __restrict__ h1) {
  const int r0 = blockIdx.x * 8;
  const int col = blockIdx.y * 256 + threadIdx.x;
  float acc[8];
#pragma unroll
  for (int u = 0; u < 8; ++u) acc[u] = 0.f;
  for (int k = 0; k < 1408; ++k) {
    float w = W1[(size_t)k * 512 + col];
#pragma unroll
    for (int u = 0; u < 8; ++u) acc[u] += pooled[(size_t)(r0 + u) * 1408 + k] * w;
  }
  for (int k = 0; k < 1024; ++k) {
    float w = W1[(size_t)(1408 + k) * 512 + col];
#pragma unroll
    for (int u = 0; u < 8; ++u) acc[u] += fs[(size_t)(r0 + u) * 1024 + k] * w;
  }
  for (int k = 0; k < FUS; ++k) {
    float w = W1[(size_t)(2432 + k) * 512 + col];
#pragma unroll
    for (int u = 0; u < 8; ++u) acc[u] += sb[(size_t)(r0 + u) * FUS + k] * w;
  }
  float bv = b1[col];
#pragma unroll
  for (int u = 0; u < 8; ++u)
    h1[(size_t)(r0 + u) * 512 + col] = fmaxf(acc[u] + bv, 0.f);
}

// ---------- h2 = relu(h1 @ W2 + b2) ----------
__global__ __launch_bounds__(256) void k_mlp2(
    const float* __restrict__ h1, const float* __restrict__ W2,
    const float* __restrict__ b2, float* __restrict__ h2) {
  const int r0 = blockIdx.x * 8, t = threadIdx.x;
  float acc[8];
#pragma unroll
  for (int u = 0; u < 8; ++u) acc[u] = 0.f;
  for (int k = 0; k < 512; ++k) {
    float w = W2[(size_t)k * 256 + t];
#pragma unroll
    for (int u = 0; u < 8; ++u) acc[u] += h1[(size_t)(r0 + u) * 512 + k] * w;
  }
  float bv = b2[t];
#pragma unroll
  for (int u = 0; u < 8; ++u)
    h2[(size_t)(r0 + u) * 256 + t] = fmaxf(acc[u] + bv, 0.f);
}

// ---------- logits = h2 @ W3 + b3 ----------
__global__ __launch_bounds__(256) void k_mlp3(
    const float* __restrict__ h2, const float* __restrict__ W3,
    const float* __restrict__ b3, float* __restrict__ out) {
  const int r0 = blockIdx.x * 8, t = threadIdx.x;
  const int u = t >> 5, oc = t & 31;
  const float* x = h2 + (size_t)(r0 + u) * 256;
  float acc = 0.f;
  for (int k = 0; k < 256; ++k) acc += x[k] * W3[(size_t)k * 32 + oc];
  out[(size_t)(r0 + u) * 32 + oc] = acc + b3[oc];
}

extern "C" void kernel_launch(void* const* d_in, const int* in_sizes, int n_in,
                              void* d_out, int out_size, void* d_ws, size_t ws_size,
                              hipStream_t stream) {
  const float* x     = (const float*)d_in[0];
  const float* eattr = (const float*)d_in[1];
  const float* W_h   = (const float*)d_in[2];
  const float* b_h   = (const float*)d_in[3];
  const float* Ws_h  = (const float*)d_in[4];
  const float* bs_h  = (const float*)d_in[5];
  const float* Wb    = (const float*)d_in[6];
  const float* bb    = (const float*)d_in[7];
  const float* Wbs   = (const float*)d_in[8];
  const float* bbs   = (const float*)d_in[9];
  const float* W_f   = (const float*)d_in[10];
  const float* b_f   = (const float*)d_in[11];
  const float* W_fs  = (const float*)d_in[12];
  const float* b_fs  = (const float*)d_in[13];
  const float* W1    = (const float*)d_in[14];
  const float* b1    = (const float*)d_in[15];
  const float* W2    = (const float*)d_in[16];
  const float* b2    = (const float*)d_in[17];
  const float* W3    = (const float*)d_in[18];
  const float* b3    = (const float*)d_in[19];
  const int*   edge  = (const int*)d_in[20];
  const int*   bbox  = (const int*)d_in[21];
  float* out = (float*)d_out;

  // ---- workspace layout (~209 MB) ----
  float* p = (float*)d_ws;
  float* feats  = p; p += (size_t)NN * FUS;
  float* sfeats = p; p += (size_t)NN * FUS;
  float* P      = p; p += (size_t)NN * CH;
  float* Q      = p; p += (size_t)NN * CH;
  float* sb     = P;                         // overlap: dead after convs
  float* fsup   = P + (size_t)NB * FUS;
  float* h1     = fsup + (size_t)NB * 1024;
  float* h2     = h1 + (size_t)NB * 512;
  float* pooled = Q;
  int* eid_arr = (int*)p;
  int* row_ptr = eid_arr + NE;
  int* deg     = row_ptr + NN + 1;
  int* cursor  = deg + NN;
  int* seg     = cursor + NN;

  hipMemsetAsync(deg, 0, 2 * NN * sizeof(int), stream);  // deg + cursor

  // ---- CSR build + bbox segments ----
  k_deg<<<(NE + 255) / 256, 256, 0, stream>>>(edge, deg);
  k_scan<<<1, 1024, 0, stream>>>(deg, row_ptr);
  k_fill<<<(NE + 255) / 256, 256, 0, stream>>>(edge, row_ptr, cursor, eid_arr);
  k_segstart<<<(NN + 255) / 256, 256, 0, stream>>>(bbox, seg);

  const int npq_grid = (NN + 31) / 32;

  // ---- conv 0 (head): both streams read x (K=8) ----
  k_node_pq<<<npq_grid, 256, 0, stream>>>(x, INCH, INCH, W_h, b_h, P, Q);
  k_conv<0><<<NN / 4, 256, 0, stream>>>(row_ptr, eid_arr, edge, eattr, P, Q,
                                        W_h + 2 * INCH * CH, feats, 0, -1);
  k_node_pq<<<npq_grid, 256, 0, stream>>>(x, INCH, INCH, Ws_h, bs_h, P, Q);
  k_conv<1><<<NN / 4, 256, 0, stream>>>(row_ptr, eid_arr, edge, eattr, P, Q,
                                        Ws_h + 2 * INCH * CH, sfeats, 0, -1);

  // ---- residual blocks (K=128) ----
  for (int i = 0; i < 2; ++i) {
    const float* Wi  = Wb  + (size_t)i * 262 * CH;
    const float* bi  = bb  + (size_t)i * CH;
    const float* Wsi = Wbs + (size_t)i * 262 * CH;
    const float* bsi = bbs + (size_t)i * CH;
    k_node_pq<<<npq_grid, 256, 0, stream>>>(feats + i * CH, FUS, CH, Wi, bi, P, Q);
    k_conv<0><<<NN / 4, 256, 0, stream>>>(row_ptr, eid_arr, edge, eattr, P, Q,
                                          Wi + 2 * CH * CH, feats, i + 1, i);
    k_node_pq<<<npq_grid, 256, 0, stream>>>(sfeats + i * CH, FUS, CH, Wsi, bsi, P, Q);
    k_conv<1><<<NN / 4, 256, 0, stream>>>(row_ptr, eid_arr, edge, eattr, P, Q,
                                          Wsi + 2 * CH * CH, sfeats, i + 1, i);
  }

  // ---- pooling + MLP head (Q dead -> becomes pooled; zero for atomicMax) ----
  hipMemsetAsync(pooled, 0, (size_t)NB * 1408 * sizeof(float), stream);
  k_pool_gemm<<<dim3((NN + 31) / 32, 4), 256, 0, stream>>>(feats, bbox, W_f, b_f,
                                                           pooled);
  k_poolraw<<<NB, 256, 0, stream>>>(feats, sfeats, seg, pooled, sb);
  k_fusion_super<<<NB / 8, 256, 0, stream>>>(sb, W_fs, b_fs, fsup);
  k_mlp1<<<dim3(NB / 8, 2), 256, 0, stream>>>(pooled, fsup, sb, W1, b1, h1);
  k_mlp2<<<NB / 8, 256, 0, stream>>>(h1, W2, b2, h2);
  k_mlp3<<<NB / 8, 256, 0, stream>>>(h2, W3, b3, out);
}

// Round 11
// 2071.645 us; speedup vs baseline: 1.4985x; 1.3207x over previous
//
#include <hip/hip_runtime.h>

#define NN     50000
#define NN_PAD 50048
#define NE     800000
#define INCH   8
#define CH     128
#define EA     6
#define NB     2000
#define NCLS   32
#define FUS    384

typedef _Float16 half8 __attribute__((ext_vector_type(8)));
typedef float f32x4 __attribute__((ext_vector_type(4)));

// ---------- degree of dst nodes ----------
__global__ __launch_bounds__(256) void k_deg(const int* __restrict__ edge,
                                             int* __restrict__ deg) {
  int e = blockIdx.x * 256 + threadIdx.x;
  if (e < NE) atomicAdd(&deg[edge[NE + e]], 1);
}

// ---------- exclusive scan of deg -> row_ptr (single block, shfl scan) ----------
__global__ __launch_bounds__(1024) void k_scan(const int* __restrict__ deg,
                                               int* __restrict__ row_ptr) {
  __shared__ int wsum[16];
  __shared__ int s_carry;
  const int t = threadIdx.x, lane = t & 63, w = t >> 6;
  if (t == 0) s_carry = 0;
  __syncthreads();
  for (int base = 0; base < NN; base += 1024) {
    int i = base + t;
    int x = (i < NN) ? deg[i] : 0;
#pragma unroll
    for (int off = 1; off < 64; off <<= 1) {
      int y = __shfl_up(x, off, 64);
      if (lane >= off) x += y;
    }
    if (lane == 63) wsum[w] = x;
    __syncthreads();
    if (w == 0 && lane < 16) {
      int s = wsum[lane];
#pragma unroll
      for (int off = 1; off < 16; off <<= 1) {
        int y = __shfl_up(s, off, 64);
        if (lane >= off) s += y;
      }
      wsum[lane] = s;
    }
    __syncthreads();
    int incl = x + ((w == 0) ? 0 : wsum[w - 1]) + s_carry;
    if (i < NN) row_ptr[i + 1] = incl;
    __syncthreads();
    if (t == 1023) s_carry = incl;
    __syncthreads();
  }
  if (t == 0) row_ptr[0] = 0;
}

// ---------- fill CSR: edge ids grouped by dst ----------
__global__ __launch_bounds__(256) void k_fill(
    const int* __restrict__ edge, const int* __restrict__ row_ptr,
    int* __restrict__ cursor, int* __restrict__ eid_arr) {
  int e = blockIdx.x * 256 + threadIdx.x;
  if (e >= NE) return;
  int d = edge[NE + e];
  int idx = row_ptr[d] + atomicAdd(&cursor[d], 1);
  eid_arr[idx] = e;
}

// ---------- segment starts from sorted bbox_idx ----------
__global__ __launch_bounds__(256) void k_segstart(const int* __restrict__ bbox,
                                                  int* __restrict__ seg) {
  int i = blockIdx.x * 256 + threadIdx.x;
  if (i >= NN) return;
  int bc = bbox[i];
  int bp = (i == 0) ? -1 : bbox[i - 1];
  for (int j = bp + 1; j <= bc; ++j) seg[j] = i;
  if (i == NN - 1)
    for (int j = bc + 1; j <= NB; ++j) seg[j] = NN;
}

// ---------- node transform: P = X@(W1-W2)+b, Q = X@W2 ----------
__global__ __launch_bounds__(256) void k_node_pq(
    const float* __restrict__ X, int ldx, int K,
    const float* __restrict__ W, const float* __restrict__ bias,
    float* __restrict__ P, float* __restrict__ Q) {
  const int t = threadIdx.x, lane = t & 63, wv = t >> 6;
  const int nbase = blockIdx.x * 32 + wv * 8;
  const int c = lane * 2;
  const float2 bv = *(const float2*)(bias + c);
  float2 pacc[8], qacc[8];
#pragma unroll
  for (int u = 0; u < 8; ++u) { pacc[u] = bv; qacc[u] = make_float2(0.f, 0.f); }
  const int xrow = min(nbase + (lane >> 3), NN - 1);
  const int xk = lane & 7;
  for (int k0 = 0; k0 < K; k0 += 8) {
    const float xv = X[(size_t)xrow * ldx + k0 + xk];
#pragma unroll
    for (int j = 0; j < 8; ++j) {
      const float2 w1 = *(const float2*)(W + (size_t)(k0 + j) * CH + c);
      const float2 w2 = *(const float2*)(W + (size_t)(K + k0 + j) * CH + c);
      const float2 wd = {w1.x - w2.x, w1.y - w2.y};
#pragma unroll
      for (int u = 0; u < 8; ++u) {
        const float xs = __shfl(xv, u * 8 + j, 64);
        pacc[u].x += xs * wd.x; pacc[u].y += xs * wd.y;
        qacc[u].x += xs * w2.x; qacc[u].y += xs * w2.y;
      }
    }
  }
#pragma unroll
  for (int u = 0; u < 8; ++u) {
    const int node = nbase + u;
    if (node < NN) {
      *(float2*)(P + (size_t)node * CH + c) = pacc[u];
      *(float2*)(Q + (size_t)node * CH + c) = qacc[u];
    }
  }
}

// ---------- CSR conv: one node per WAVE, lane-batched edge meta + shfl ----------
template <int MODE>  // 0 = max, 1 = mean
__global__ __launch_bounds__(256) void k_conv(
    const int* __restrict__ row_ptr, const int* __restrict__ eid_arr,
    const int* __restrict__ edge, const float* __restrict__ eattr,
    const float* __restrict__ P, const float* __restrict__ Q,
    const float* __restrict__ C, float* __restrict__ outf,
    int cur, int prev) {
  const int t = threadIdx.x;
  const int lane = t & 63;
  const int node = blockIdx.x * 4 + (t >> 6);
  const int c = lane * 2;
  float2 cw[EA];
#pragma unroll
  for (int j = 0; j < EA; ++j) cw[j] = *(const float2*)(C + j * CH + c);
  int i0 = __builtin_amdgcn_readfirstlane(row_ptr[node]);
  int i1 = __builtin_amdgcn_readfirstlane(row_ptr[node + 1]);
  const float2 q = *(const float2*)(Q + (size_t)node * CH + c);
  float a0 = 0.f, a1 = 0.f;
  for (int base = i0; base < i1; base += 64) {
    const int cnt = min(64, i1 - base);
    int s_l = 0;
    float ea0 = 0.f, ea1 = 0.f, ea2 = 0.f, ea3 = 0.f, ea4 = 0.f, ea5 = 0.f;
    if (lane < cnt) {
      int e = eid_arr[base + lane];      // coalesced
      s_l = edge[e];                     // gather
      const float* ep = eattr + (size_t)e * EA;
      ea0 = ep[0]; ea1 = ep[1]; ea2 = ep[2];
      ea3 = ep[3]; ea4 = ep[4]; ea5 = ep[5];
    }
#define EDGE_BODY(J)                                                       \
    {                                                                      \
      int s = __shfl(s_l, (J), 64);                                        \
      float e0 = __shfl(ea0, (J), 64), e1 = __shfl(ea1, (J), 64);          \
      float e2 = __shfl(ea2, (J), 64), e3 = __shfl(ea3, (J), 64);          \
      float e4 = __shfl(ea4, (J), 64), e5 = __shfl(ea5, (J), 64);          \
      const float2 pv = *(const float2*)(P + (size_t)s * CH + c);          \
      float v0 = pv.x + q.x, v1 = pv.y + q.y;                              \
      v0 += e0 * cw[0].x; v1 += e0 * cw[0].y;                              \
      v0 += e1 * cw[1].x; v1 += e1 * cw[1].y;                              \
      v0 += e2 * cw[2].x; v1 += e2 * cw[2].y;                              \
      v0 += e3 * cw[3].x; v1 += e3 * cw[3].y;                              \
      v0 += e4 * cw[4].x; v1 += e4 * cw[4].y;                              \
      v0 += e5 * cw[5].x; v1 += e5 * cw[5].y;                              \
      if (MODE == 0) { a0 = fmaxf(a0, v0); a1 = fmaxf(a1, v1); }           \
      else           { a0 += fmaxf(v0, 0.f); a1 += fmaxf(v1, 0.f); }       \
    }
    int j = 0;
    for (; j + 8 <= cnt; j += 8) {
      EDGE_BODY(j)     EDGE_BODY(j + 1) EDGE_BODY(j + 2) EDGE_BODY(j + 3)
      EDGE_BODY(j + 4) EDGE_BODY(j + 5) EDGE_BODY(j + 6) EDGE_BODY(j + 7)
    }
    for (; j < cnt; ++j) EDGE_BODY(j)
#undef EDGE_BODY
  }
  if (MODE == 1) {
    float inv = 1.f / fmaxf((float)(i1 - i0), 1.f);
    a0 *= inv; a1 *= inv;
  }
  size_t o = (size_t)node * FUS + (size_t)cur * CH + c;
  if (prev >= 0) {
    const float2 pr = *(const float2*)(outf + (size_t)node * FUS + (size_t)prev * CH + c);
    a0 += pr.x; a1 += pr.y;
  }
  float2 ov = {a0, a1};
  *(float2*)(outf + o) = ov;
}

// ---------- convert feats -> f16, rows >= NN zero-padded ----------
__global__ __launch_bounds__(256) void k_cvtA(const float* __restrict__ feats,
                                              _Float16* __restrict__ fh) {
  const size_t off = ((size_t)blockIdx.x * 256 + threadIdx.x) * 8;
  const int row = (int)(off / FUS);
  half8 v;
  if (row < NN) {
    const float4 f0 = *(const float4*)(feats + off);
    const float4 f1 = *(const float4*)(feats + off + 4);
    v[0] = (_Float16)f0.x; v[1] = (_Float16)f0.y;
    v[2] = (_Float16)f0.z; v[3] = (_Float16)f0.w;
    v[4] = (_Float16)f1.x; v[5] = (_Float16)f1.y;
    v[6] = (_Float16)f1.z; v[7] = (_Float16)f1.w;
  } else {
#pragma unroll
    for (int j = 0; j < 8; ++j) v[j] = (_Float16)0.f;
  }
  *(half8*)(fh + off) = v;
}

// ---------- convert + pack W_f into B-fragment order ----------
// For ktile c (12 of K=32), ntile t (64 of N=16), lane L: element j holds
// W[c*32 + (L>>4)*8 + j][t*16 + (L&15)] -> contiguous 16B per lane in GEMM.
__global__ __launch_bounds__(64) void k_cvtB(const float* __restrict__ Wf,
                                             _Float16* __restrict__ wh) {
  const int c = blockIdx.x >> 6;      // 0..11
  const int tile = blockIdx.x & 63;   // 0..63
  const int L = threadIdx.x;
  const int n = tile * 16 + (L & 15);
  const int k0 = c * 32 + (L >> 4) * 8;
  half8 v;
#pragma unroll
  for (int j = 0; j < 8; ++j) v[j] = (_Float16)Wf[(size_t)(k0 + j) * 1024 + n];
  *(half8*)(wh + (((size_t)(c * 64 + tile)) * 64 + L) * 8) = v;
}

// ---------- fusion GEMM on matrix cores + segment max ----------
// Block: 64 rows x 128 cols, 4 waves; wave w owns n-tiles {w*2, w*2+1} x all
// 4 m-tiles. mfma_f32_16x16x32_f16, fp32 acc (A: m=lane&15,k=quad*8+j;
// B symmetric; D: col=lane&15, row=quad*4+reg). C staged to 32KB LDS, then
// 128 threads run-merge 64 bbox-sorted rows per column -> ~460 atomicMax/blk.
__global__ __launch_bounds__(256) void k_pool_mfma(
    const _Float16* __restrict__ fh, const _Float16* __restrict__ wh,
    const int* __restrict__ bbox, const float* __restrict__ bf,
    float* __restrict__ pooled) {
  __shared__ float cl[64 * 128];
  const int t = threadIdx.x, lane = t & 63, wv = t >> 6;
  const int nbase = blockIdx.x * 64;
  const int cg = blockIdx.y;          // column group of 128
  const int m = lane & 15, quad = lane >> 4;
  f32x4 acc[4][2];
#pragma unroll
  for (int i = 0; i < 4; ++i)
#pragma unroll
    for (int nt = 0; nt < 2; ++nt) acc[i][nt] = (f32x4){0.f, 0.f, 0.f, 0.f};
  const _Float16* ap = fh + (size_t)(nbase + m) * FUS + quad * 8;
  const _Float16* bp = wh + ((size_t)(cg * 8 + wv * 2) * 64 + lane) * 8;
#pragma unroll
  for (int ks = 0; ks < 12; ++ks) {
    const half8 b0 = *(const half8*)(bp + (size_t)ks * 32768);
    const half8 b1 = *(const half8*)(bp + (size_t)ks * 32768 + 512);
#pragma unroll
    for (int i = 0; i < 4; ++i) {
      const half8 a = *(const half8*)(ap + (size_t)(i * 16) * FUS + ks * 32);
      acc[i][0] = __builtin_amdgcn_mfma_f32_16x16x32_f16(a, b0, acc[i][0], 0, 0, 0);
      acc[i][1] = __builtin_amdgcn_mfma_f32_16x16x32_f16(a, b1, acc[i][1], 0, 0, 0);
    }
  }
#pragma unroll
  for (int i = 0; i < 4; ++i)
#pragma unroll
    for (int nt = 0; nt < 2; ++nt) {
      const int col = wv * 32 + nt * 16 + m;
#pragma unroll
      for (int r = 0; r < 4; ++r)
        cl[(i * 16 + quad * 4 + r) * 128 + col] = acc[i][nt][r];
    }
  __syncthreads();
  if (t < 128) {
    const int gcol = cg * 128 + t;
    const float bias = bf[gcol];
    int curb = -1;
    float mx = 0.f;
    for (int row = 0; row < 64; ++row) {
      const int node = nbase + row;
      if (node >= NN) break;
      const int bid = bbox[node];
      const float v = fmaxf(cl[row * 128 + t] + bias, 0.f);
      if (bid != curb) {
        if (curb >= 0)
          atomicMax((unsigned*)(pooled + (size_t)curb * 1408 + gcol),
                    __float_as_uint(mx));
        curb = bid;
        mx = v;
      } else {
        mx = fmaxf(mx, v);
      }
    }
    if (curb >= 0)
      atomicMax((unsigned*)(pooled + (size_t)curb * 1408 + gcol),
                __float_as_uint(mx));
  }
}

// ---------- raw-feats bbox max + sfeats bbox mean ----------
__global__ __launch_bounds__(256) void k_poolraw(
    const float* __restrict__ feats, const float* __restrict__ sfeats,
    const int* __restrict__ seg, float* __restrict__ pooled,
    float* __restrict__ sb) {
  const int b = blockIdx.x, t = threadIdx.x;
  if (t >= 192) return;
  const int c2 = t * 2;
  const int n0 = __builtin_amdgcn_readfirstlane(seg[b]);
  const int n1 = __builtin_amdgcn_readfirstlane(seg[b + 1]);
  float2 fmx = {0.f, 0.f}, ss = {0.f, 0.f};
  for (int n = n0; n < n1; ++n) {
    const float2 f2 = *(const float2*)(feats + (size_t)n * FUS + c2);
    fmx.x = fmaxf(fmx.x, f2.x); fmx.y = fmaxf(fmx.y, f2.y);
    const float2 s2 = *(const float2*)(sfeats + (size_t)n * FUS + c2);
    ss.x += s2.x; ss.y += s2.y;
  }
  *(float2*)(pooled + (size_t)b * 1408 + 1024 + c2) = fmx;
  const float inv = 1.f / fmaxf((float)(n1 - n0), 1.f);
  float2 o = {ss.x * inv, ss.y * inv};
  *(float2*)(sb + (size_t)b * FUS + c2) = o;
}

// ---------- fusion_super = relu(sb @ Wfs + bfs) ----------
__global__ __launch_bounds__(256) void k_fusion_super(
    const float* __restrict__ sb, const float* __restrict__ Wfs,
    const float* __restrict__ bfs, float* __restrict__ fs) {
  const int r0 = blockIdx.x * 8, t = threadIdx.x;
  float acc[8][4];
#pragma unroll
  for (int u = 0; u < 8; ++u)
    acc[u][0] = acc[u][1] = acc[u][2] = acc[u][3] = 0.f;
  for (int k = 0; k < FUS; ++k) {
    const float4 w = *(const float4*)(Wfs + (size_t)k * 1024 + t * 4);
#pragma unroll
    for (int u = 0; u < 8; ++u) {
      float x = sb[(size_t)(r0 + u) * FUS + k];
      acc[u][0] += x * w.x; acc[u][1] += x * w.y;
      acc[u][2] += x * w.z; acc[u][3] += x * w.w;
    }
  }
  const float4 b4 = *(const float4*)(bfs + t * 4);
#pragma unroll
  for (int u = 0; u < 8; ++u) {
    float4 o = {fmaxf(acc[u][0] + b4.x, 0.f), fmaxf(acc[u][1] + b4.y, 0.f),
                fmaxf(acc[u][2] + b4.z, 0.f), fmaxf(acc[u][3] + b4.w, 0.f)};
    *(float4*)(fs + (size_t)(r0 + u) * 1024 + t * 4) = o;
  }
}

// ---------- h1 = relu(concat(pooled, fs, sb) @ W1 + b1), column-split ----------
__global__ __launch_bounds__(256) void k_mlp1(
    const float* __restrict__ pooled, const float* __restrict__ fs,
    const float* __restrict__ sb, const float* __restrict__ W1,
    const float* __restrict__ b1, float* __restrict__ h1) {
  const int r0 = blockIdx.x * 8;
  const int col = blockIdx.y * 256 + threadIdx.x;
  float acc[8];
#pragma unroll
  for (int u = 0; u < 8; ++u) acc[u] = 0.f;
  for (int k = 0; k < 1408; ++k) {
    float w = W1[(size_t)k * 512 + col];
#pragma unroll
    for (int u = 0; u < 8; ++u) acc[u] += pooled[(size_t)(r0 + u) * 1408 + k] * w;
  }
  for (int k = 0; k < 1024; ++k) {
    float w = W1[(size_t)(1408 + k) * 512 + col];
#pragma unroll
    for (int u = 0; u < 8; ++u) acc[u] += fs[(size_t)(r0 + u) * 1024 + k] * w;
  }
  for (int k = 0; k < FUS; ++k) {
    float w = W1[(size_t)(2432 + k) * 512 + col];
#pragma unroll
    for (int u = 0; u < 8; ++u) acc[u] += sb[(size_t)(r0 + u) * FUS + k] * w;
  }
  float bv = b1[col];
#pragma unroll
  for (int u = 0; u < 8; ++u)
    h1[(size_t)(r0 + u) * 512 + col] = fmaxf(acc[u] + bv, 0.f);
}

// ---------- h2 = relu(h1 @ W2 + b2) ----------
__global__ __launch_bounds__(256) void k_mlp2(
    const float* __restrict__ h1, const float* __restrict__ W2,
    const float* __restrict__ b2, float* __restrict__ h2) {
  const int r0 = blockIdx.x * 8, t = threadIdx.x;
  float acc[8];
#pragma unroll
  for (int u = 0; u < 8; ++u) acc[u] = 0.f;
  for (int k = 0; k < 512; ++k) {
    float w = W2[(size_t)k * 256 + t];
#pragma unroll
    for (int u = 0; u < 8; ++u) acc[u] += h1[(size_t)(r0 + u) * 512 + k] * w;
  }
  float bv = b2[t];
#pragma unroll
  for (int u = 0; u < 8; ++u)
    h2[(size_t)(r0 + u) * 256 + t] = fmaxf(acc[u] + bv, 0.f);
}

// ---------- logits = h2 @ W3 + b3 ----------
__global__ __launch_bounds__(256) void k_mlp3(
    const float* __restrict__ h2, const float* __restrict__ W3,
    const float* __restrict__ b3, float* __restrict__ out) {
  const int r0 = blockIdx.x * 8, t = threadIdx.x;
  const int u = t >> 5, oc = t & 31;
  const float* x = h2 + (size_t)(r0 + u) * 256;
  float acc = 0.f;
  for (int k = 0; k < 256; ++k) acc += x[k] * W3[(size_t)k * 32 + oc];
  out[(size_t)(r0 + u) * 32 + oc] = acc + b3[oc];
}

extern "C" void kernel_launch(void* const* d_in, const int* in_sizes, int n_in,
                              void* d_out, int out_size, void* d_ws, size_t ws_size,
                              hipStream_t stream) {
  const float* x     = (const float*)d_in[0];
  const float* eattr = (const float*)d_in[1];
  const float* W_h   = (const float*)d_in[2];
  const float* b_h   = (const float*)d_in[3];
  const float* Ws_h  = (const float*)d_in[4];
  const float* bs_h  = (const float*)d_in[5];
  const float* Wb    = (const float*)d_in[6];
  const float* bb    = (const float*)d_in[7];
  const float* Wbs   = (const float*)d_in[8];
  const float* bbs   = (const float*)d_in[9];
  const float* W_f   = (const float*)d_in[10];
  const float* b_f   = (const float*)d_in[11];
  const float* W_fs  = (const float*)d_in[12];
  const float* b_fs  = (const float*)d_in[13];
  const float* W1    = (const float*)d_in[14];
  const float* b1    = (const float*)d_in[15];
  const float* W2    = (const float*)d_in[16];
  const float* b2    = (const float*)d_in[17];
  const float* W3    = (const float*)d_in[18];
  const float* b3    = (const float*)d_in[19];
  const int*   edge  = (const int*)d_in[20];
  const int*   bbox  = (const int*)d_in[21];
  float* out = (float*)d_out;

  // ---- workspace layout (~209 MB, unchanged footprint) ----
  float* p = (float*)d_ws;
  float* feats  = p; p += (size_t)NN * FUS;       // 76.8 MB
  float* sfeats = p; p += (size_t)NN * FUS;       // 76.8 MB
  float* PQ     = p; p += (size_t)2 * NN * CH;    // 51.2 MB = 12.8M floats
  float* P = PQ;
  float* Q = PQ + (size_t)NN * CH;
  // overlays inside PQ (live only AFTER the last k_conv):
  _Float16* featsH = (_Float16*)PQ;                         // 9.609M floats
  _Float16* WfH    = featsH + (size_t)NN_PAD * FUS;         // 0.197M floats
  float* pooled    = (float*)(WfH + (size_t)FUS * 1024);    // 2.816M floats
  //   total: 12.62M <= 12.8M floats. After k_pool_mfma, featsH region reused:
  float* sb   = PQ;                                         // 0.768M
  float* fsup = sb + (size_t)NB * FUS;                      // 2.048M
  float* h1   = fsup + (size_t)NB * 1024;                   // 1.024M
  float* h2   = h1 + (size_t)NB * 512;                      // 0.512M (4.35M <= 9.6M)
  int* eid_arr = (int*)p;
  int* row_ptr = eid_arr + NE;
  int* deg     = row_ptr + NN + 1;
  int* cursor  = deg + NN;
  int* seg     = cursor + NN;

  hipMemsetAsync(deg, 0, 2 * NN * sizeof(int), stream);  // deg + cursor

  // ---- CSR build + bbox segments ----
  k_deg<<<(NE + 255) / 256, 256, 0, stream>>>(edge, deg);
  k_scan<<<1, 1024, 0, stream>>>(deg, row_ptr);
  k_fill<<<(NE + 255) / 256, 256, 0, stream>>>(edge, row_ptr, cursor, eid_arr);
  k_segstart<<<(NN + 255) / 256, 256, 0, stream>>>(bbox, seg);

  const int npq_grid = (NN + 31) / 32;

  // ---- conv 0 (head): both streams read x (K=8) ----
  k_node_pq<<<npq_grid, 256, 0, stream>>>(x, INCH, INCH, W_h, b_h, P, Q);
  k_conv<0><<<NN / 4, 256, 0, stream>>>(row_ptr, eid_arr, edge, eattr, P, Q,
                                        W_h + 2 * INCH * CH, feats, 0, -1);
  k_node_pq<<<npq_grid, 256, 0, stream>>>(x, INCH, INCH, Ws_h, bs_h, P, Q);
  k_conv<1><<<NN / 4, 256, 0, stream>>>(row_ptr, eid_arr, edge, eattr, P, Q,
                                        Ws_h + 2 * INCH * CH, sfeats, 0, -1);

  // ---- residual blocks (K=128) ----
  for (int i = 0; i < 2; ++i) {
    const float* Wi  = Wb  + (size_t)i * 262 * CH;
    const float* bi  = bb  + (size_t)i * CH;
    const float* Wsi = Wbs + (size_t)i * 262 * CH;
    const float* bsi = bbs + (size_t)i * CH;
    k_node_pq<<<npq_grid, 256, 0, stream>>>(feats + i * CH, FUS, CH, Wi, bi, P, Q);
    k_conv<0><<<NN / 4, 256, 0, stream>>>(row_ptr, eid_arr, edge, eattr, P, Q,
                                          Wi + 2 * CH * CH, feats, i + 1, i);
    k_node_pq<<<npq_grid, 256, 0, stream>>>(sfeats + i * CH, FUS, CH, Wsi, bsi, P, Q);
    k_conv<1><<<NN / 4, 256, 0, stream>>>(row_ptr, eid_arr, edge, eattr, P, Q,
                                          Wsi + 2 * CH * CH, sfeats, i + 1, i);
  }

  // ---- pooling: f16 converts + MFMA GEMM + atomicMax epilogue ----
  // (PQ region is dead from here; pooled zeroed for uint-bitpattern max)
  k_cvtA<<<(int)(((size_t)NN_PAD * FUS / 8) / 256), 256, 0, stream>>>(feats, featsH);
  k_cvtB<<<12 * 64, 64, 0, stream>>>(W_f, WfH);
  hipMemsetAsync(pooled, 0, (size_t)NB * 1408 * sizeof(float), stream);
  k_pool_mfma<<<dim3(NN_PAD / 64, 8), 256, 0, stream>>>(featsH, WfH, bbox, b_f,
                                                        pooled);
  k_poolraw<<<NB, 256, 0, stream>>>(feats, sfeats, seg, pooled, sb);
  k_fusion_super<<<NB / 8, 256, 0, stream>>>(sb, W_fs, b_fs, fsup);
  k_mlp1<<<dim3(NB / 8, 2), 256, 0, stream>>>(pooled, fsup, sb, W1, b1, h1);
  k_mlp2<<<NB / 8, 256, 0, stream>>>(h1, W2, b2, h2);
  k_mlp3<<<NB / 8, 256, 0, stream>>>(h2, W3, b3, out);
}